// Round 3
// baseline (793.346 us; speedup 1.0000x reference)
//
#include <hip/hip_runtime.h>
#include <stdint.h>

// ---- problem constants (from reference) ----
#define N_NODES 16000
#define MPAD_   16128   // N_NODES padded to multiple of 256 for the 256^2 GEMM
#define B_      32
#define NPG_    500
#define E_      256000
#define F_      1024
#define OD_     128
#define DD_     80
#define TD_     32
#define NH_     4
#define DH_     8
#define DFF_    128
#define LSUB_   128
#define MAXLEN_ 512
#define EPS_    1e-5f
#define SLOPE_  0.01f

typedef __bf16 bf16x8 __attribute__((ext_vector_type(8)));
typedef float  f32x4  __attribute__((ext_vector_type(4)));

__device__ __forceinline__ float leaky(float v) { return v >= 0.f ? v : SLOPE_ * v; }

__device__ __forceinline__ unsigned short f2bf(float f) {
  unsigned u = __float_as_uint(f);
  u += 0x7FFFu + ((u >> 16) & 1u);   // RNE
  return (unsigned short)(u >> 16);
}
__device__ __forceinline__ float bf2f(unsigned short u) {
  return __uint_as_float((unsigned)u << 16);
}

__device__ __forceinline__ void gld_lds16(const void* g, void* l) {
  __builtin_amdgcn_global_load_lds(
      (const __attribute__((address_space(1))) unsigned int*)g,
      (__attribute__((address_space(3))) unsigned int*)l, 16, 0, 0);
}

// ---- fp32 -> bf16 conversion for two tensors (grid.y selects) ----
__global__ void k_f2bf2(const float* __restrict__ in0, const float* __restrict__ in1,
                        unsigned short* __restrict__ out0, unsigned short* __restrict__ out1,
                        int n4) {
  const float* in = blockIdx.y ? in1 : in0;
  unsigned short* out = blockIdx.y ? out1 : out0;
  int i = blockIdx.x * blockDim.x + threadIdx.x;
  int stride = gridDim.x * blockDim.x;
  for (; i < n4; i += stride) {
    float4 v = ((const float4*)in)[i];
    ushort4 o;
    o.x = f2bf(v.x); o.y = f2bf(v.y); o.z = f2bf(v.z); o.w = f2bf(v.w);
    ((ushort4*)out)[i] = o;
  }
}

// ---- 256x256 8-phase bf16 MFMA GEMM: C[M,N] = A[M,K]*B[N,K]^T, bf16 out. ----
#define LDSA(bf, ks, row) (*(const bf16x8*)&lds[(bf)*16384 + (ks)*8192 + (row)*32 + rs])
#define LDSB(bf, ks, row) (*(const bf16x8*)&lds[32768 + (bf)*16384 + (ks)*8192 + (row)*32 + rs])
#define STG_A(bf, R, kti) do { \
  gld_lds16(&Ag[(size_t)(mBase + (R) + r4) * 1024 + (kti) * 64 + c4],      &lds[(bf)*16384 + (R)*32 + t*8]); \
  gld_lds16(&Ag[(size_t)(mBase + (R) + r4) * 1024 + (kti) * 64 + 32 + c4], &lds[(bf)*16384 + 8192 + (R)*32 + t*8]); \
} while (0)
#define STG_B(bf, R, kti) do { \
  gld_lds16(&Bg[(size_t)(nBase + (R) + r4) * 1024 + (kti) * 64 + c4],      &lds[32768 + (bf)*16384 + (R)*32 + t*8]); \
  gld_lds16(&Bg[(size_t)(nBase + (R) + r4) * 1024 + (kti) * 64 + 32 + c4], &lds[32768 + (bf)*16384 + 8192 + (R)*32 + t*8]); \
} while (0)
#define RD_Q0(bf) do { \
  _Pragma("unroll") for (int mi = 0; mi < 4; ++mi) \
  _Pragma("unroll") for (int ks = 0; ks < 2; ++ks) \
    aLo[mi][ks] = LDSA(bf, ks, wrow * 128 + mi * 16 + l15); \
  _Pragma("unroll") for (int ni = 0; ni < 2; ++ni) \
  _Pragma("unroll") for (int ks = 0; ks < 2; ++ks) \
    bLo[ni][ks] = LDSB(bf, ks, wcol * 64 + ni * 16 + l15); \
} while (0)
#define RD_BHI(bf) do { \
  _Pragma("unroll") for (int ni = 0; ni < 2; ++ni) \
  _Pragma("unroll") for (int ks = 0; ks < 2; ++ks) \
    bHi[ni][ks] = LDSB(bf, ks, wcol * 64 + (2 + ni) * 16 + l15); \
} while (0)
#define RD_AHI(bf) do { \
  _Pragma("unroll") for (int mi = 0; mi < 4; ++mi) \
  _Pragma("unroll") for (int ks = 0; ks < 2; ++ks) \
    aHi[mi][ks] = LDSA(bf, ks, wrow * 128 + (4 + mi) * 16 + l15); \
} while (0)
#define MM_Q0() do { __builtin_amdgcn_s_setprio(1); \
  _Pragma("unroll") for (int mi = 0; mi < 4; ++mi) \
  _Pragma("unroll") for (int ni = 0; ni < 2; ++ni) \
  _Pragma("unroll") for (int ks = 0; ks < 2; ++ks) \
    acc[mi][ni] = __builtin_amdgcn_mfma_f32_16x16x32_bf16(aLo[mi][ks], bLo[ni][ks], acc[mi][ni], 0, 0, 0); \
  __builtin_amdgcn_s_setprio(0); } while (0)
#define MM_Q1() do { __builtin_amdgcn_s_setprio(1); \
  _Pragma("unroll") for (int mi = 0; mi < 4; ++mi) \
  _Pragma("unroll") for (int ni = 0; ni < 2; ++ni) \
  _Pragma("unroll") for (int ks = 0; ks < 2; ++ks) \
    acc[mi][2 + ni] = __builtin_amdgcn_mfma_f32_16x16x32_bf16(aLo[mi][ks], bHi[ni][ks], acc[mi][2 + ni], 0, 0, 0); \
  __builtin_amdgcn_s_setprio(0); } while (0)
#define MM_Q3() do { __builtin_amdgcn_s_setprio(1); \
  _Pragma("unroll") for (int mi = 0; mi < 4; ++mi) \
  _Pragma("unroll") for (int ni = 0; ni < 2; ++ni) \
  _Pragma("unroll") for (int ks = 0; ks < 2; ++ks) \
    acc[4 + mi][2 + ni] = __builtin_amdgcn_mfma_f32_16x16x32_bf16(aHi[mi][ks], bHi[ni][ks], acc[4 + mi][2 + ni], 0, 0, 0); \
  __builtin_amdgcn_s_setprio(0); } while (0)
#define MM_Q2() do { __builtin_amdgcn_s_setprio(1); \
  _Pragma("unroll") for (int mi = 0; mi < 4; ++mi) \
  _Pragma("unroll") for (int ni = 0; ni < 2; ++ni) \
  _Pragma("unroll") for (int ks = 0; ks < 2; ++ks) \
    acc[4 + mi][ni] = __builtin_amdgcn_mfma_f32_16x16x32_bf16(aHi[mi][ks], bLo[ni][ks], acc[4 + mi][ni], 0, 0, 0); \
  __builtin_amdgcn_s_setprio(0); } while (0)
#define BAR() do { __builtin_amdgcn_sched_barrier(0); __builtin_amdgcn_s_barrier(); \
                   __builtin_amdgcn_sched_barrier(0); } while (0)
#define LGKM0() do { asm volatile("s_waitcnt lgkmcnt(0)" ::: "memory"); \
                     __builtin_amdgcn_sched_barrier(0); } while (0)
#define VM4() do { asm volatile("s_waitcnt vmcnt(4)" ::: "memory"); } while (0)
#define VM0() do { asm volatile("s_waitcnt vmcnt(0)" ::: "memory"); } while (0)

__global__ __launch_bounds__(512, 2) void k_gemm256(const unsigned short* __restrict__ Ag,
                                                    const unsigned short* __restrict__ Bg,
                                                    unsigned short* __restrict__ Cg) {
  __shared__ short lds[65536];   // 128 KiB: A [2][2][256][32] | B at +32768
  const int j  = blockIdx.x;     // 0..251
  const int x8 = j & 7;          // stable XCD id under round-robin dispatch
  const int chunk = (x8 < 4) ? x8 * 32 : 128 + (x8 - 4) * 31;  // bijective (m204)
  const int pos = chunk + (j >> 3);
  const int mb = pos >> 2, nb = pos & 3;   // nb fastest within XCD chunk
  const size_t g = blockIdx.z;
  Ag += g * (size_t)MPAD_ * 1024;
  Bg += g * (size_t)1024 * 1024;
  Cg += g * (size_t)MPAD_ * 1024;
  const int t = threadIdx.x;
  const int lane = t & 63, wave = t >> 6;
  const int wrow = wave >> 2, wcol = wave & 3;
  const int quad = lane >> 4, l15 = lane & 15;
  const int mBase = mb * 256, nBase = nb * 256;
  const int r4 = t >> 2;                                // 0..127 staging row
  const int c4 = (((t & 3) - ((t >> 3) & 3)) & 3) * 8;  // source chunk swizzle
  const int rs = ((quad + (l15 >> 1)) & 3) * 8;         // read slot swizzle

  f32x4 acc[8][4];
  f32x4 zero = {0.f, 0.f, 0.f, 0.f};
#pragma unroll
  for (int i = 0; i < 8; ++i)
#pragma unroll
    for (int jn = 0; jn < 4; ++jn) acc[i][jn] = zero;

  bf16x8 aLo[4][2], aHi[4][2], bLo[2][2], bHi[2][2];

  // prologue: T0 fully into buf0; B halves of T1 into buf1
  STG_A(0, 0, 0); STG_A(0, 128, 0); STG_B(0, 0, 0); STG_B(0, 128, 0);
  STG_B(1, 0, 1); STG_B(1, 128, 1);
  VM4();   // T0's 8 loads landed (leaves B(1) pair in flight)
  BAR();

  for (int kt = 0; kt < 16; kt += 2) {
    const bool s2 = (kt + 2) < 16;
    const bool s3 = (kt + 3) < 16;
    RD_Q0(0);
    STG_A(1, 0, kt + 1);
    BAR(); LGKM0(); MM_Q0(); BAR();
    RD_BHI(0);
    STG_A(1, 128, kt + 1);
    BAR(); LGKM0(); MM_Q1(); BAR();
    RD_AHI(0);
    if (s2) STG_B(0, 0, kt + 2);
    BAR(); LGKM0(); MM_Q3(); BAR();
    if (s2) { STG_B(0, 128, kt + 2); VM4(); } else VM0();
    BAR(); MM_Q2(); BAR();
    RD_Q0(1);
    if (s2) STG_A(0, 0, kt + 2);
    BAR(); LGKM0(); MM_Q0(); BAR();
    RD_BHI(1);
    if (s2) STG_A(0, 128, kt + 2);
    BAR(); LGKM0(); MM_Q1(); BAR();
    RD_AHI(1);
    if (s3) STG_B(1, 0, kt + 3);
    BAR(); LGKM0(); MM_Q3(); BAR();
    if (s3) { STG_B(1, 128, kt + 3); VM4(); }
    BAR(); MM_Q2(); BAR();
  }

#pragma unroll
  for (int mi = 0; mi < 8; ++mi)
#pragma unroll
    for (int ni = 0; ni < 4; ++ni)
#pragma unroll
      for (int r = 0; r < 4; ++r) {
        int grow = mBase + wrow * 128 + mi * 16 + quad * 4 + r;
        int gcol = nBase + wcol * 64 + ni * 16 + l15;
        Cg[(size_t)grow * 1024 + gcol] = f2bf(acc[mi][ni][r]);
      }
}

// ---- degree histogram over dst (grid.y = graph) ----
__global__ void k_hist(const int* __restrict__ ei0, const int* __restrict__ ei1,
                       int* __restrict__ cnt, int e, int n) {
  const int g = blockIdx.y;
  const int* dst = (g ? ei1 : ei0) + e;
  int i = blockIdx.x * 256 + threadIdx.x;
  if (i < e) atomicAdd(&cnt[g * n + dst[i]], 1);
}

// ---- per-graph block: exclusive scan of cnt -> rowstart/cursor; dinv = rsqrt(cnt+1) ----
__global__ void k_scan(const int* __restrict__ cnt_all, int* __restrict__ rowstart_all,
                       int* __restrict__ cursor_all, float* __restrict__ dinv_all, int n) {
  const int g = blockIdx.x;
  const int* cnt = cnt_all + g * n;
  int* rowstart = rowstart_all + g * (n + 1);
  int* cursor   = cursor_all + g * n;
  float* dinv   = dinv_all + g * n;
  __shared__ int part[256];
  __shared__ int base[257];
  int t = threadIdx.x;
  int chunk = (n + 255) >> 8;
  int s = 0;
  for (int j = 0; j < chunk; ++j) {
    int idx = t * chunk + j;
    if (idx < n) s += cnt[idx];
  }
  part[t] = s;
  __syncthreads();
  if (t == 0) {
    int a = 0;
    for (int i = 0; i < 256; ++i) { base[i] = a; a += part[i]; }
    base[256] = a;
  }
  __syncthreads();
  int a = base[t];
  for (int j = 0; j < chunk; ++j) {
    int idx = t * chunk + j;
    if (idx < n) {
      int c = cnt[idx];
      rowstart[idx] = a; cursor[idx] = a; a += c;
      dinv[idx] = rsqrtf((float)c + 1.0f);
    }
  }
  if (t == 0) rowstart[n] = base[256];
}

// ---- scatter edges to CSR, precomputing edge weight dinv[s]*dinv[d] (grid.y = graph) ----
__global__ void k_scatter(const int* __restrict__ ei0, const int* __restrict__ ei1,
                          const float* __restrict__ dinv_all, int* __restrict__ cursor_all,
                          int* __restrict__ csr_all, float* __restrict__ csrw_all,
                          int e, int n) {
  const int g = blockIdx.y;
  const int* ei = g ? ei1 : ei0;
  int i = blockIdx.x * 256 + threadIdx.x;
  if (i < e) {
    int s = ei[i], d = ei[e + i];
    int p = atomicAdd(&cursor_all[g * n + d], 1);
    csr_all[(size_t)g * e + p]  = s;
    csrw_all[(size_t)g * e + p] = dinv_all[g * n + s] * dinv_all[g * n + d];
  }
}

// ---- sliced CSR gather, 4 dst/block (4 waves), no LDS staging.
// grid (8 slices, 4000, 2 graphs): slice == linear%8 -> stable XCD mapping,
// per-XCD h working set one 4 MB slice; z dispatched after all of z=0.
// Neighbor index loads are wave-uniform (broadcast, 1 line); h reads are
// 64-lane x 4B = 256B contiguous. Removes 2 barriers + LDS round-trip/chunk. ----
__global__ __launch_bounds__(256) void k_gather(const ushort2* __restrict__ h2_all,
                                                const float* __restrict__ dinv_all,
                                                const int* __restrict__ rowstart_all,
                                                const int* __restrict__ csr_all,
                                                const float* __restrict__ csrw_all,
                                                ushort2* __restrict__ agg2_all) {
  const int g = blockIdx.z;
  const ushort2* h2 = h2_all + (size_t)g * MPAD_ * 512;
  const float* dinv = dinv_all + (size_t)g * N_NODES;
  const int* rowstart = rowstart_all + (size_t)g * (N_NODES + 1);
  const int* csr = csr_all + (size_t)g * E_;
  const float* csrw = csrw_all + (size_t)g * E_;
  ushort2* agg2 = agg2_all + (size_t)g * N_NODES * 512;
  const int sl = blockIdx.x;                       // feature slice 0..7
  const int i  = blockIdx.y * 4 + (threadIdx.x >> 6);  // dst node
  const int lane = threadIdx.x & 63;
  const size_t fo = (size_t)sl * 64 + lane;
  const float di = dinv[i];
  ushort2 sv = h2[(size_t)i * 512 + fo];
  const float selfw = di * di;
  float ax = bf2f(sv.x) * selfw, ay = bf2f(sv.y) * selfw;
  const int beg = rowstart[i], end = rowstart[i + 1];
  int j = beg;
  for (; j + 4 <= end; j += 4) {
    int s0 = csr[j], s1 = csr[j + 1], s2 = csr[j + 2], s3 = csr[j + 3];
    float w0 = csrw[j], w1 = csrw[j + 1], w2 = csrw[j + 2], w3 = csrw[j + 3];
    ushort2 v0 = h2[(size_t)s0 * 512 + fo];
    ushort2 v1 = h2[(size_t)s1 * 512 + fo];
    ushort2 v2 = h2[(size_t)s2 * 512 + fo];
    ushort2 v3 = h2[(size_t)s3 * 512 + fo];
    ax += bf2f(v0.x) * w0 + bf2f(v1.x) * w1 + bf2f(v2.x) * w2 + bf2f(v3.x) * w3;
    ay += bf2f(v0.y) * w0 + bf2f(v1.y) * w1 + bf2f(v2.y) * w2 + bf2f(v3.y) * w3;
  }
  for (; j < end; ++j) {
    int s0 = csr[j];
    float w0 = csrw[j];
    ushort2 v0 = h2[(size_t)s0 * 512 + fo];
    ax += bf2f(v0.x) * w0; ay += bf2f(v0.y) * w0;
  }
  ushort2 o; o.x = f2bf(ax); o.y = f2bf(ay);
  agg2[(size_t)i * 512 + fo] = o;
}

// ---- mean pool of leaky(agg + bias); grid.z in [0,64): g = z>>5, b = z&31 ----
__global__ void k_pool(const unsigned short* __restrict__ agg_all,
                       const float* __restrict__ bias0, const float* __restrict__ bias1,
                       float* __restrict__ pooled_all) {
  int f = blockIdx.x * 256 + threadIdx.x;  // 0..1023
  int z = blockIdx.z;
  int g = z >> 5, b = z & 31;
  const unsigned short* agg = agg_all + (size_t)g * N_NODES * F_;
  const float* bias = g ? bias1 : bias0;
  float* pooled = pooled_all + (size_t)g * B_ * F_;
  int r0 = blockIdx.y * 100;
  float bf = bias[f];
  float s = 0.f;
  for (int r = 0; r < 100; ++r)
    s += leaky(bf2f(agg[(size_t)(b * NPG_ + r0 + r) * F_ + f]) + bf);
  atomicAdd(&pooled[b * F_ + f], s);
}

// ---- fc: coalesced w reads + LDS-staged pooled + wave shuffle-reduce.
// Old version: per-thread 1024-iter scalar gather over w rows = 64 distinct
// cachelines per wave-load from L2. New: lanes read w[o][f] f-coalesced. ----
__global__ __launch_bounds__(256) void k_fc(const float* __restrict__ pooled_all,
                     const float* __restrict__ w0, const float* __restrict__ w1,
                     const float* __restrict__ bias0, const float* __restrict__ bias1,
                     float* __restrict__ out0, float* __restrict__ out1) {
  __shared__ float ps[F_];
  const int b = blockIdx.x, g = blockIdx.y, t = threadIdx.x;
  const float* p = pooled_all + (size_t)g * B_ * F_ + b * F_;
  const float* w = g ? w1 : w0;
  const float* bias = g ? bias1 : bias0;
  float* out = g ? out1 : out0;
  ((float4*)ps)[t] = ((const float4*)p)[t];   // 256*16B = 4KB = F_ floats
  __syncthreads();
  const int wave = t >> 6, lane = t & 63;
  for (int oo = 0; oo < 32; ++oo) {
    const int o = wave * 32 + oo;
    const float* wr = w + (size_t)o * F_;
    float a = 0.f;
#pragma unroll
    for (int c = 0; c < 16; ++c) a += wr[c * 64 + lane] * ps[c * 64 + lane];
#pragma unroll
    for (int m = 1; m < 64; m <<= 1) a += __shfl_xor(a, m, 64);
    if (lane == 0) out[b * OD_ + o] = leaky(a * (1.f / 500.f) + bias[o]);
  }
}

// ---- ragged pack ----
__global__ void k_pack(const float* __restrict__ m0, const float* __restrict__ m1,
                       const float* __restrict__ m2, const float* __restrict__ m3,
                       const int* __restrict__ l0, const int* __restrict__ l1,
                       const int* __restrict__ l2, const int* __restrict__ l3,
                       const float* __restrict__ rw, const float* __restrict__ rb,
                       float* __restrict__ seq) {
  __shared__ float xs[DD_];
  const int p = blockIdx.x, b = blockIdx.y, k = blockIdx.z;
  const float* mas = (k == 0) ? m0 : (k == 1) ? m1 : (k == 2) ? m2 : m3;
  const int*   lk  = (k == 0) ? l0 : (k == 1) ? l1 : (k == 2) ? l2 : l3;
  const int len = lk[b];
  if (p >= len) return;
  int off = 0;
  if (k > 0) off += l0[b];
  if (k > 1) off += l1[b];
  if (k > 2) off += l2[b];
  const int t = threadIdx.x;  // 64
  for (int d = t; d < DD_; d += 64) xs[d] = mas[(size_t)(b * LSUB_ + p) * DD_ + d];
  __syncthreads();
  if (t < TD_) {
    float v;
    if (t < TD_ - 2) {
      float a = rb[t];
      const float* w = &rw[t * DD_];
      for (int d = 0; d < DD_; ++d) a += xs[d] * w[d];
      v = a;
    } else if (t == TD_ - 2) {
      v = (k == 0 || k == 2) ? 1.f : 0.f;
    } else {
      v = (k < 2) ? 1.f : 0.f;
    }
    seq[((size_t)b * MAXLEN_ + off + p) * TD_ + t] = v;
  }
}

__global__ void k_totlen(const int* __restrict__ l0, const int* __restrict__ l1,
                         const int* __restrict__ l2, const int* __restrict__ l3,
                         int* __restrict__ tot) {
  int b = threadIdx.x;
  if (b < B_) tot[b] = l0[b] + l1[b] + l2[b] + l3[b];
}

// ---- qkv projection (skip dead rows) ----
__global__ void k_qkv(const float* __restrict__ xt, const float* __restrict__ w,
                      const float* __restrict__ bias, const int* __restrict__ tot,
                      float* __restrict__ qkv) {
  __shared__ float xs[TD_];
  const int row = blockIdx.x;
  if ((row & (MAXLEN_ - 1)) >= tot[row >> 9]) return;
  const int t = threadIdx.x;      // 128
  if (t < TD_) xs[t] = xt[(size_t)row * TD_ + t];
  __syncthreads();
  if (t < 3 * TD_) {
    float a = bias[t];
    const float* wr = &w[t * TD_];
#pragma unroll
    for (int k = 0; k < TD_; ++k) a += xs[k] * wr[k];
    qkv[(size_t)row * 96 + t] = a;
  }
}

// ---- attention: one lane-pair per query, single pass (scores |s|<~1) ----
__global__ __launch_bounds__(128) void k_attn(const float* __restrict__ qkv,
                                              const int* __restrict__ tot,
                                              float* __restrict__ obuf) {
  __shared__ float Kl[MAXLEN_ * DH_];
  __shared__ float Vl[MAXLEN_ * DH_];
  const int h = blockIdx.x, b = blockIdx.y, qz = blockIdx.z;
  const int t = threadIdx.x;  // 128
  const int L = tot[b];
  if (qz * 64 >= L) return;
  const float* base = &qkv[(size_t)b * MAXLEN_ * 96];
  for (int i = t; i < L * DH_; i += 128) {
    int p = i >> 3, d = i & 7;
    Kl[i] = base[p * 96 + 32 + h * 8 + d];
    Vl[i] = base[p * 96 + 64 + h * 8 + d];
  }
  __syncthreads();
  const int qi = qz * 64 + (t >> 1);
  if (qi >= L) return;
  const int half = t & 1;
  const float scale = 0.35355339059327373f;  // 1/sqrt(8)
  float q[8];
#pragma unroll
  for (int d = 0; d < 8; ++d) q[d] = base[qi * 96 + h * 8 + d] * scale;

  float l0 = 0.f, l1 = 0.f;
  float a0[8] = {0, 0, 0, 0, 0, 0, 0, 0};
  float a1[8] = {0, 0, 0, 0, 0, 0, 0, 0};
  int j = half;
  for (; j + 2 < L; j += 4) {
    const float* kr0 = &Kl[j * 8];
    const float* kr1 = &Kl[(j + 2) * 8];
    float s0 = 0.f, s1 = 0.f;
#pragma unroll
    for (int d = 0; d < 8; ++d) { s0 += q[d] * kr0[d]; s1 += q[d] * kr1[d]; }
    float p0 = __expf(s0), p1 = __expf(s1);
    l0 += p0; l1 += p1;
    const float* vr0 = &Vl[j * 8];
    const float* vr1 = &Vl[(j + 2) * 8];
#pragma unroll
    for (int d = 0; d < 8; ++d) { a0[d] += p0 * vr0[d]; a1[d] += p1 * vr1[d]; }
  }
  for (; j < L; j += 2) {
    const float* kr = &Kl[j * 8];
    float s = 0.f;
#pragma unroll
    for (int d = 0; d < 8; ++d) s += q[d] * kr[d];
    float p = __expf(s);
    l0 += p;
    const float* vr = &Vl[j * 8];
#pragma unroll
    for (int d = 0; d < 8; ++d) a0[d] += p * vr[d];
  }
  float l = l0 + l1;
#pragma unroll
  for (int d = 0; d < 8; ++d) a0[d] += a1[d];
  l += __shfl_xor(l, 1);
#pragma unroll
  for (int d = 0; d < 8; ++d) a0[d] += __shfl_xor(a0[d], 1);
  float inv = 1.f / l;
  const int dbase = half * 4;
  float4 o;
  o.x = a0[dbase + 0] * inv; o.y = a0[dbase + 1] * inv;
  o.z = a0[dbase + 2] * inv; o.w = a0[dbase + 3] * inv;
  *(float4*)&obuf[((size_t)b * MAXLEN_ + qi) * TD_ + h * 8 + dbase] = o;
}

// ---- fused post-attention: out-proj + residual + LN1 + FFN + residual + LN2.
// One row per block (uniform early-return => barriers safe). Replaces two
// 16k-block launches per layer with one; removes one xt round-trip. ----
__global__ __launch_bounds__(128) void k_post(const float* __restrict__ obuf,
                                              const float* __restrict__ ow,
                                              const float* __restrict__ ob,
                                              const float* __restrict__ l1w,
                                              const float* __restrict__ l1b,
                                              const float* __restrict__ f1w,
                                              const float* __restrict__ f1b,
                                              const float* __restrict__ f2w,
                                              const float* __restrict__ f2b,
                                              const float* __restrict__ l2w,
                                              const float* __restrict__ l2b,
                                              const int* __restrict__ tot,
                                              float* __restrict__ xt) {
  const int r = blockIdx.x, t = threadIdx.x;  // 128
  if ((r & (MAXLEN_ - 1)) >= tot[r >> 9]) return;
  __shared__ float xs[TD_];   // LN1 output
  __shared__ float hb[DFF_];
  if (t < TD_) {
    const float* orow = &obuf[(size_t)r * TD_];
    float a = ob[t] + xt[(size_t)r * TD_ + t];
    const float* wr = &ow[t * TD_];
#pragma unroll
    for (int k = 0; k < TD_; ++k) a += orow[k] * wr[k];
    float s1 = a, s2 = a * a;
#pragma unroll
    for (int m = 1; m < 32; m <<= 1) {
      s1 += __shfl_xor(s1, m, 32);
      s2 += __shfl_xor(s2, m, 32);
    }
    float mean = s1 * (1.f / 32.f);
    float var  = s2 * (1.f / 32.f) - mean * mean;
    xs[t] = (a - mean) * rsqrtf(var + EPS_) * l1w[t] + l1b[t];
  }
  __syncthreads();
  {
    float a = f1b[t];
    const float* wr = &f1w[t * TD_];
#pragma unroll
    for (int k = 0; k < TD_; ++k) a += xs[k] * wr[k];
    hb[t] = fmaxf(a, 0.f);
  }
  __syncthreads();
  if (t < TD_) {
    float a = f2b[t] + xs[t];
    const float* wr = &f2w[t * DFF_];
#pragma unroll
    for (int k = 0; k < DFF_; ++k) a += hb[k] * wr[k];
    float s1 = a, s2 = a * a;
#pragma unroll
    for (int m = 1; m < 32; m <<= 1) {
      s1 += __shfl_xor(s1, m, 32);
      s2 += __shfl_xor(s2, m, 32);
    }
    float mean = s1 * (1.f / 32.f);
    float var  = s2 * (1.f / 32.f) - mean * mean;
    xt[(size_t)r * TD_ + t] = (a - mean) * rsqrtf(var + EPS_) * l2w[t] + l2b[t];
  }
}

// ---- fused masked mean + final linear ----
__global__ __launch_bounds__(256) void k_maskfinal(const float* __restrict__ xt,
                                                   const int* __restrict__ tot,
                                                   const float* __restrict__ x1,
                                                   const float* __restrict__ x2,
                                                   const float* __restrict__ fw,
                                                   const float* __restrict__ fb,
                                                   float* __restrict__ out) {
  __shared__ float sbuf[8][32];
  __shared__ float mo[TD_];
  const int b = blockIdx.x, t = threadIdx.x;  // 256
  const int j = t & 31, c = t >> 5;
  const int L = tot[b];
  float s = 0.f;
  for (int p = c; p < L; p += 8) s += xt[((size_t)b * MAXLEN_ + p) * TD_ + j];
  sbuf[c][j] = s;
  __syncthreads();
  if (t < 32) {
    float a = 0.f;
#pragma unroll
    for (int cc = 0; cc < 8; ++cc) a += sbuf[cc][t];
    mo[t] = a / (float)L;
  }
  __syncthreads();
  if (t < 64) {
    float s2 = 0.f;
    for (int i = t; i < 2 * OD_ + TD_; i += 64) {
      float cv = (i < OD_) ? x1[b * OD_ + i]
               : (i < 2 * OD_) ? x2[b * OD_ + (i - OD_)]
               : mo[i - 2 * OD_];
      s2 += fw[i] * cv;
    }
#pragma unroll
    for (int m = 1; m < 64; m <<= 1) s2 += __shfl_xor(s2, m, 64);
    if (t == 0) out[b] = s2 + fb[0];
  }
}

extern "C" void kernel_launch(void* const* d_in, const int* in_sizes, int n_in,
                              void* d_out, int out_size, void* d_ws, size_t ws_size,
                              hipStream_t stream) {
  (void)in_sizes; (void)n_in; (void)out_size; (void)ws_size;
  const float* pro_x[2]  = {(const float*)d_in[0], (const float*)d_in[1]};
  const int*   pro_ei[2] = {(const int*)d_in[2], (const int*)d_in[3]};
  const float* mas[4]    = {(const float*)d_in[6], (const float*)d_in[8],
                            (const float*)d_in[10], (const float*)d_in[12]};
  const int*   lens[4]   = {(const int*)d_in[7], (const int*)d_in[9],
                            (const int*)d_in[11], (const int*)d_in[13]};
  const float* gw[2]  = {(const float*)d_in[14], (const float*)d_in[16]};
  const float* gb[2]  = {(const float*)d_in[15], (const float*)d_in[17]};
  const float* fcw[2] = {(const float*)d_in[18], (const float*)d_in[20]};
  const float* fcb[2] = {(const float*)d_in[19], (const float*)d_in[21]};
  const float* red_w = (const float*)d_in[22];
  const float* red_b = (const float*)d_in[23];
  const float* attn_in_w  = (const float*)d_in[24];
  const float* attn_in_b  = (const float*)d_in[25];
  const float* attn_out_w = (const float*)d_in[26];
  const float* attn_out_b = (const float*)d_in[27];
  const float* ln1_w = (const float*)d_in[28];
  const float* ln1_b = (const float*)d_in[29];
  const float* ln2_w = (const float*)d_in[30];
  const float* ln2_b = (const float*)d_in[31];
  const float* ff1_w = (const float*)d_in[32];
  const float* ff1_b = (const float*)d_in[33];
  const float* ff2_w = (const float*)d_in[34];
  const float* ff2_b = (const float*)d_in[35];
  const float* final_w = (const float*)d_in[36];
  const float* final_b = (const float*)d_in[37];
  float* out = (float*)d_out;

  char* p = (char*)d_ws;
  auto carve = [&](size_t bytes) -> void* {
    void* r = (void*)p;
    p += (bytes + 255) & ~(size_t)255;
    return r;
  };
  unsigned short* xb  = (unsigned short*)carve((size_t)2 * MPAD_ * F_ * 2);
  unsigned short* Wb  = (unsigned short*)carve((size_t)2 * F_ * F_ * 2);
  unsigned short* h   = (unsigned short*)carve((size_t)2 * MPAD_ * F_ * 2);
  unsigned short* agg = (unsigned short*)carve((size_t)2 * N_NODES * F_ * 2);
  int*   cnt      = (int*)carve((size_t)2 * N_NODES * 4);
  float* dinv     = (float*)carve((size_t)2 * N_NODES * 4);
  int*   rowstart = (int*)carve((size_t)2 * (N_NODES + 1) * 4);
  int*   cursor   = (int*)carve((size_t)2 * N_NODES * 4);
  int*   csr      = (int*)carve((size_t)2 * E_ * 4);
  float* csrw     = (float*)carve((size_t)2 * E_ * 4);
  float* pooled   = (float*)carve((size_t)2 * B_ * F_ * 4);
  float* xg[2];
  xg[0] = (float*)carve((size_t)B_ * OD_ * 4);
  xg[1] = (float*)carve((size_t)B_ * OD_ * 4);
  float* seq    = (float*)carve((size_t)B_ * MAXLEN_ * TD_ * 4);
  float* qkv    = (float*)carve((size_t)B_ * MAXLEN_ * 96 * 4);
  float* obuf   = (float*)carve((size_t)B_ * MAXLEN_ * TD_ * 4);
  int*   totlen = (int*)carve((size_t)B_ * 4);

  // ---- GCN branches (merged across both graphs) ----
  k_f2bf2<<<dim3(1024, 2), 256, 0, stream>>>(pro_x[0], pro_x[1], xb,
                                             xb + (size_t)MPAD_ * F_, (N_NODES * F_) / 4);
  k_f2bf2<<<dim3(512, 2), 256, 0, stream>>>(gw[0], gw[1], Wb, Wb + (size_t)F_ * F_,
                                            (F_ * F_) / 4);
  k_gemm256<<<dim3(252, 1, 2), 512, 0, stream>>>(xb, Wb, h);
  hipMemsetAsync(cnt, 0, (size_t)2 * N_NODES * 4, stream);
  k_hist<<<dim3(1000, 2), 256, 0, stream>>>(pro_ei[0], pro_ei[1], cnt, E_, N_NODES);
  k_scan<<<2, 256, 0, stream>>>(cnt, rowstart, cursor, dinv, N_NODES);
  k_scatter<<<dim3(1000, 2), 256, 0, stream>>>(pro_ei[0], pro_ei[1], dinv, cursor,
                                               csr, csrw, E_, N_NODES);
  k_gather<<<dim3(8, 4000, 2), 256, 0, stream>>>((const ushort2*)h, dinv, rowstart,
                                                 csr, csrw, (ushort2*)agg);
  hipMemsetAsync(pooled, 0, (size_t)2 * B_ * F_ * 4, stream);
  k_pool<<<dim3(4, 5, 64), 256, 0, stream>>>(agg, gb[0], gb[1], pooled);
  k_fc<<<dim3(B_, 2), 256, 0, stream>>>(pooled, fcw[0], fcw[1], fcb[0], fcb[1],
                                        xg[0], xg[1]);

  // ---- ragged pack (no memset: rows [0,tot) fully written; dead rows unread) ----
  k_pack<<<dim3(LSUB_, B_, 4), 64, 0, stream>>>(mas[0], mas[1], mas[2], mas[3],
                                                lens[0], lens[1], lens[2], lens[3],
                                                red_w, red_b, seq);
  k_totlen<<<1, 64, 0, stream>>>(lens[0], lens[1], lens[2], lens[3], totlen);

  // ---- transformer (2 layers) ----
  for (int li = 0; li < 2; ++li) {
    k_qkv<<<B_ * MAXLEN_, 128, 0, stream>>>(seq, attn_in_w + (size_t)li * 96 * TD_,
                                            attn_in_b + (size_t)li * 96, totlen, qkv);
    k_attn<<<dim3(NH_, B_, 8), 128, 0, stream>>>(qkv, totlen, obuf);
    k_post<<<B_ * MAXLEN_, 128, 0, stream>>>(
        obuf, attn_out_w + (size_t)li * TD_ * TD_, attn_out_b + (size_t)li * TD_,
        ln1_w + (size_t)li * TD_, ln1_b + (size_t)li * TD_,
        ff1_w + (size_t)li * DFF_ * TD_, ff1_b + (size_t)li * DFF_,
        ff2_w + (size_t)li * TD_ * DFF_, ff2_b + (size_t)li * TD_,
        ln2_w + (size_t)li * TD_, ln2_b + (size_t)li * TD_, totlen, seq);
  }

  // ---- fused masked mean + final ----
  k_maskfinal<<<B_, 256, 0, stream>>>(seq, totlen, xg[0], xg[1], final_w, final_b, out);
}

// Round 4
// 752.863 us; speedup vs baseline: 1.0538x; 1.0538x over previous
//
#include <hip/hip_runtime.h>
#include <stdint.h>

// ---- problem constants (from reference) ----
#define N_NODES 16000
#define MPAD_   16128   // N_NODES padded to multiple of 256 for the 256^2 GEMM
#define B_      32
#define NPG_    500
#define E_      256000
#define F_      1024
#define OD_     128
#define DD_     80
#define TD_     32
#define NH_     4
#define DH_     8
#define DFF_    128
#define LSUB_   128
#define MAXLEN_ 512
#define EPS_    1e-5f
#define SLOPE_  0.01f

typedef __bf16 bf16x8 __attribute__((ext_vector_type(8)));
typedef float  f32x4  __attribute__((ext_vector_type(4)));

__device__ __forceinline__ float leaky(float v) { return v >= 0.f ? v : SLOPE_ * v; }

__device__ __forceinline__ unsigned short f2bf(float f) {
  unsigned u = __float_as_uint(f);
  u += 0x7FFFu + ((u >> 16) & 1u);   // RNE
  return (unsigned short)(u >> 16);
}
__device__ __forceinline__ float bf2f(unsigned short u) {
  return __uint_as_float((unsigned)u << 16);
}

__device__ __forceinline__ void gld_lds16(const void* g, void* l) {
  __builtin_amdgcn_global_load_lds(
      (const __attribute__((address_space(1))) unsigned int*)g,
      (__attribute__((address_space(3))) unsigned int*)l, 16, 0, 0);
}

// ---- fp32 -> bf16 conversion for two tensors (grid.y selects) ----
__global__ void k_f2bf2(const float* __restrict__ in0, const float* __restrict__ in1,
                        unsigned short* __restrict__ out0, unsigned short* __restrict__ out1,
                        int n4) {
  const float* in = blockIdx.y ? in1 : in0;
  unsigned short* out = blockIdx.y ? out1 : out0;
  int i = blockIdx.x * blockDim.x + threadIdx.x;
  int stride = gridDim.x * blockDim.x;
  for (; i < n4; i += stride) {
    float4 v = ((const float4*)in)[i];
    ushort4 o;
    o.x = f2bf(v.x); o.y = f2bf(v.y); o.z = f2bf(v.z); o.w = f2bf(v.w);
    ((ushort4*)out)[i] = o;
  }
}

// ---- 256x256 8-phase bf16 MFMA GEMM: C[M,N] = A[M,K]*B[N,K]^T, bf16 out. ----
#define LDSA(bf, ks, row) (*(const bf16x8*)&lds[(bf)*16384 + (ks)*8192 + (row)*32 + rs])
#define LDSB(bf, ks, row) (*(const bf16x8*)&lds[32768 + (bf)*16384 + (ks)*8192 + (row)*32 + rs])
#define STG_A(bf, R, kti) do { \
  gld_lds16(&Ag[(size_t)(mBase + (R) + r4) * 1024 + (kti) * 64 + c4],      &lds[(bf)*16384 + (R)*32 + t*8]); \
  gld_lds16(&Ag[(size_t)(mBase + (R) + r4) * 1024 + (kti) * 64 + 32 + c4], &lds[(bf)*16384 + 8192 + (R)*32 + t*8]); \
} while (0)
#define STG_B(bf, R, kti) do { \
  gld_lds16(&Bg[(size_t)(nBase + (R) + r4) * 1024 + (kti) * 64 + c4],      &lds[32768 + (bf)*16384 + (R)*32 + t*8]); \
  gld_lds16(&Bg[(size_t)(nBase + (R) + r4) * 1024 + (kti) * 64 + 32 + c4], &lds[32768 + (bf)*16384 + 8192 + (R)*32 + t*8]); \
} while (0)
#define RD_Q0(bf) do { \
  _Pragma("unroll") for (int mi = 0; mi < 4; ++mi) \
  _Pragma("unroll") for (int ks = 0; ks < 2; ++ks) \
    aLo[mi][ks] = LDSA(bf, ks, wrow * 128 + mi * 16 + l15); \
  _Pragma("unroll") for (int ni = 0; ni < 2; ++ni) \
  _Pragma("unroll") for (int ks = 0; ks < 2; ++ks) \
    bLo[ni][ks] = LDSB(bf, ks, wcol * 64 + ni * 16 + l15); \
} while (0)
#define RD_BHI(bf) do { \
  _Pragma("unroll") for (int ni = 0; ni < 2; ++ni) \
  _Pragma("unroll") for (int ks = 0; ks < 2; ++ks) \
    bHi[ni][ks] = LDSB(bf, ks, wcol * 64 + (2 + ni) * 16 + l15); \
} while (0)
#define RD_AHI(bf) do { \
  _Pragma("unroll") for (int mi = 0; mi < 4; ++mi) \
  _Pragma("unroll") for (int ks = 0; ks < 2; ++ks) \
    aHi[mi][ks] = LDSA(bf, ks, wrow * 128 + (4 + mi) * 16 + l15); \
} while (0)
#define MM_Q0() do { __builtin_amdgcn_s_setprio(1); \
  _Pragma("unroll") for (int mi = 0; mi < 4; ++mi) \
  _Pragma("unroll") for (int ni = 0; ni < 2; ++ni) \
  _Pragma("unroll") for (int ks = 0; ks < 2; ++ks) \
    acc[mi][ni] = __builtin_amdgcn_mfma_f32_16x16x32_bf16(aLo[mi][ks], bLo[ni][ks], acc[mi][ni], 0, 0, 0); \
  __builtin_amdgcn_s_setprio(0); } while (0)
#define MM_Q1() do { __builtin_amdgcn_s_setprio(1); \
  _Pragma("unroll") for (int mi = 0; mi < 4; ++mi) \
  _Pragma("unroll") for (int ni = 0; ni < 2; ++ni) \
  _Pragma("unroll") for (int ks = 0; ks < 2; ++ks) \
    acc[mi][2 + ni] = __builtin_amdgcn_mfma_f32_16x16x32_bf16(aLo[mi][ks], bHi[ni][ks], acc[mi][2 + ni], 0, 0, 0); \
  __builtin_amdgcn_s_setprio(0); } while (0)
#define MM_Q3() do { __builtin_amdgcn_s_setprio(1); \
  _Pragma("unroll") for (int mi = 0; mi < 4; ++mi) \
  _Pragma("unroll") for (int ni = 0; ni < 2; ++ni) \
  _Pragma("unroll") for (int ks = 0; ks < 2; ++ks) \
    acc[4 + mi][2 + ni] = __builtin_amdgcn_mfma_f32_16x16x32_bf16(aHi[mi][ks], bHi[ni][ks], acc[4 + mi][2 + ni], 0, 0, 0); \
  __builtin_amdgcn_s_setprio(0); } while (0)
#define MM_Q2() do { __builtin_amdgcn_s_setprio(1); \
  _Pragma("unroll") for (int mi = 0; mi < 4; ++mi) \
  _Pragma("unroll") for (int ni = 0; ni < 2; ++ni) \
  _Pragma("unroll") for (int ks = 0; ks < 2; ++ks) \
    acc[4 + mi][ni] = __builtin_amdgcn_mfma_f32_16x16x32_bf16(aHi[mi][ks], bLo[ni][ks], acc[4 + mi][ni], 0, 0, 0); \
  __builtin_amdgcn_s_setprio(0); } while (0)
#define BAR() do { __builtin_amdgcn_sched_barrier(0); __builtin_amdgcn_s_barrier(); \
                   __builtin_amdgcn_sched_barrier(0); } while (0)
#define LGKM0() do { asm volatile("s_waitcnt lgkmcnt(0)" ::: "memory"); \
                     __builtin_amdgcn_sched_barrier(0); } while (0)
#define VM4() do { asm volatile("s_waitcnt vmcnt(4)" ::: "memory"); } while (0)
#define VM0() do { asm volatile("s_waitcnt vmcnt(0)" ::: "memory"); } while (0)

__global__ __launch_bounds__(512, 2) void k_gemm256(const unsigned short* __restrict__ Ag,
                                                    const unsigned short* __restrict__ Bg,
                                                    unsigned short* __restrict__ Cg) {
  __shared__ short lds[65536];   // 128 KiB: A [2][2][256][32] | B at +32768
  const int j  = blockIdx.x;     // 0..251
  const int x8 = j & 7;          // stable XCD id under round-robin dispatch
  const int chunk = (x8 < 4) ? x8 * 32 : 128 + (x8 - 4) * 31;  // bijective (m204)
  const int pos = chunk + (j >> 3);
  const int mb = pos >> 2, nb = pos & 3;   // nb fastest within XCD chunk
  const size_t g = blockIdx.z;
  Ag += g * (size_t)MPAD_ * 1024;
  Bg += g * (size_t)1024 * 1024;
  Cg += g * (size_t)MPAD_ * 1024;
  const int t = threadIdx.x;
  const int lane = t & 63, wave = t >> 6;
  const int wrow = wave >> 2, wcol = wave & 3;
  const int quad = lane >> 4, l15 = lane & 15;
  const int mBase = mb * 256, nBase = nb * 256;
  const int r4 = t >> 2;                                // 0..127 staging row
  const int c4 = (((t & 3) - ((t >> 3) & 3)) & 3) * 8;  // source chunk swizzle
  const int rs = ((quad + (l15 >> 1)) & 3) * 8;         // read slot swizzle

  f32x4 acc[8][4];
  f32x4 zero = {0.f, 0.f, 0.f, 0.f};
#pragma unroll
  for (int i = 0; i < 8; ++i)
#pragma unroll
    for (int jn = 0; jn < 4; ++jn) acc[i][jn] = zero;

  bf16x8 aLo[4][2], aHi[4][2], bLo[2][2], bHi[2][2];

  // prologue: T0 fully into buf0; B halves of T1 into buf1
  STG_A(0, 0, 0); STG_A(0, 128, 0); STG_B(0, 0, 0); STG_B(0, 128, 0);
  STG_B(1, 0, 1); STG_B(1, 128, 1);
  VM4();   // T0's 8 loads landed (leaves B(1) pair in flight)
  BAR();

  for (int kt = 0; kt < 16; kt += 2) {
    const bool s2 = (kt + 2) < 16;
    const bool s3 = (kt + 3) < 16;
    RD_Q0(0);
    STG_A(1, 0, kt + 1);
    BAR(); LGKM0(); MM_Q0(); BAR();
    RD_BHI(0);
    STG_A(1, 128, kt + 1);
    BAR(); LGKM0(); MM_Q1(); BAR();
    RD_AHI(0);
    if (s2) STG_B(0, 0, kt + 2);
    BAR(); LGKM0(); MM_Q3(); BAR();
    if (s2) { STG_B(0, 128, kt + 2); VM4(); } else VM0();
    BAR(); MM_Q2(); BAR();
    RD_Q0(1);
    if (s2) STG_A(0, 0, kt + 2);
    BAR(); LGKM0(); MM_Q0(); BAR();
    RD_BHI(1);
    if (s2) STG_A(0, 128, kt + 2);
    BAR(); LGKM0(); MM_Q1(); BAR();
    RD_AHI(1);
    if (s3) STG_B(1, 0, kt + 3);
    BAR(); LGKM0(); MM_Q3(); BAR();
    if (s3) { STG_B(1, 128, kt + 3); VM4(); }
    BAR(); MM_Q2(); BAR();
  }

#pragma unroll
  for (int mi = 0; mi < 8; ++mi)
#pragma unroll
    for (int ni = 0; ni < 4; ++ni)
#pragma unroll
      for (int r = 0; r < 4; ++r) {
        int grow = mBase + wrow * 128 + mi * 16 + quad * 4 + r;
        int gcol = nBase + wcol * 64 + ni * 16 + l15;
        Cg[(size_t)grow * 1024 + gcol] = f2bf(acc[mi][ni][r]);
      }
}

// ---- degree histogram over dst (grid.y = graph) ----
__global__ void k_hist(const int* __restrict__ ei0, const int* __restrict__ ei1,
                       int* __restrict__ cnt, int e, int n) {
  const int g = blockIdx.y;
  const int* dst = (g ? ei1 : ei0) + e;
  int i = blockIdx.x * 256 + threadIdx.x;
  if (i < e) atomicAdd(&cnt[g * n + dst[i]], 1);
}

// ---- per-graph block: exclusive scan of cnt -> rowstart/cursor; dinv = rsqrt(cnt+1) ----
__global__ void k_scan(const int* __restrict__ cnt_all, int* __restrict__ rowstart_all,
                       int* __restrict__ cursor_all, float* __restrict__ dinv_all, int n) {
  const int g = blockIdx.x;
  const int* cnt = cnt_all + g * n;
  int* rowstart = rowstart_all + g * (n + 1);
  int* cursor   = cursor_all + g * n;
  float* dinv   = dinv_all + g * n;
  __shared__ int part[256];
  __shared__ int base[257];
  int t = threadIdx.x;
  int chunk = (n + 255) >> 8;
  int s = 0;
  for (int j = 0; j < chunk; ++j) {
    int idx = t * chunk + j;
    if (idx < n) s += cnt[idx];
  }
  part[t] = s;
  __syncthreads();
  if (t == 0) {
    int a = 0;
    for (int i = 0; i < 256; ++i) { base[i] = a; a += part[i]; }
    base[256] = a;
  }
  __syncthreads();
  int a = base[t];
  for (int j = 0; j < chunk; ++j) {
    int idx = t * chunk + j;
    if (idx < n) {
      int c = cnt[idx];
      rowstart[idx] = a; cursor[idx] = a; a += c;
      dinv[idx] = rsqrtf((float)c + 1.0f);
    }
  }
  if (t == 0) rowstart[n] = base[256];
}

// ---- scatter edges to CSR, fused record {src, weight-bits} (grid.y = graph) ----
__global__ void k_scatter(const int* __restrict__ ei0, const int* __restrict__ ei1,
                          const float* __restrict__ dinv_all, int* __restrict__ cursor_all,
                          int2* __restrict__ csre_all, int e, int n) {
  const int g = blockIdx.y;
  const int* ei = g ? ei1 : ei0;
  int i = blockIdx.x * 256 + threadIdx.x;
  if (i < e) {
    int s = ei[i], d = ei[e + i];
    int p = atomicAdd(&cursor_all[g * n + d], 1);
    float w = dinv_all[g * n + s] * dinv_all[g * n + d];
    csre_all[(size_t)g * e + p] = make_int2(s, __float_as_int(w));
  }
}

// ---- sliced CSR gather v3: 4 slices x ushort4 (8B/lane), fused int2 edge recs.
// R3 counters: 154.7us, VALUBusy 49% = instruction-overhead-bound (4.1M thin
// 256B edge-visits, ~4 useful ops of ~16). v3 halves visits (2.05M x 512B)
// and halves edge-meta loads (one int2 vs csr+csrw). Per-XCD slice set grows
// 4->8MB (partial L2 thrash, LLC-backed; we were at 20% of L2 BW, headroom).
// grid (4 slices, 4000, 2 graphs); 4 dst/block (4 waves). ----
__global__ __launch_bounds__(256) void k_gather(const ushort4* __restrict__ h4_all,
                                                const float* __restrict__ dinv_all,
                                                const int* __restrict__ rowstart_all,
                                                const int2* __restrict__ csre_all,
                                                ushort4* __restrict__ agg4_all) {
  const int g = blockIdx.z;
  const ushort4* h4 = h4_all + (size_t)g * MPAD_ * 256;
  const float* dinv = dinv_all + (size_t)g * N_NODES;
  const int* rowstart = rowstart_all + (size_t)g * (N_NODES + 1);
  const int2* csre = csre_all + (size_t)g * E_;
  ushort4* agg4 = agg4_all + (size_t)g * N_NODES * 256;
  const int sl = blockIdx.x;                           // feature slice 0..3
  const int i  = blockIdx.y * 4 + (threadIdx.x >> 6);  // dst node
  const int lane = threadIdx.x & 63;
  const int fo4 = sl * 64 + lane;                      // ushort4 index in row
  const float di = dinv[i];
  ushort4 sv = h4[(size_t)i * 256 + fo4];
  const float selfw = di * di;
  float a0 = bf2f(sv.x) * selfw, a1 = bf2f(sv.y) * selfw;
  float a2 = bf2f(sv.z) * selfw, a3 = bf2f(sv.w) * selfw;
  const int beg = rowstart[i], end = rowstart[i + 1];
  int j = beg;
  for (; j + 4 <= end; j += 4) {
    int2 e0 = csre[j], e1 = csre[j + 1], e2 = csre[j + 2], e3 = csre[j + 3];
    ushort4 v0 = h4[(size_t)e0.x * 256 + fo4];
    ushort4 v1 = h4[(size_t)e1.x * 256 + fo4];
    ushort4 v2 = h4[(size_t)e2.x * 256 + fo4];
    ushort4 v3 = h4[(size_t)e3.x * 256 + fo4];
    float w0 = __int_as_float(e0.y), w1 = __int_as_float(e1.y);
    float w2 = __int_as_float(e2.y), w3 = __int_as_float(e3.y);
    a0 += bf2f(v0.x) * w0 + bf2f(v1.x) * w1 + bf2f(v2.x) * w2 + bf2f(v3.x) * w3;
    a1 += bf2f(v0.y) * w0 + bf2f(v1.y) * w1 + bf2f(v2.y) * w2 + bf2f(v3.y) * w3;
    a2 += bf2f(v0.z) * w0 + bf2f(v1.z) * w1 + bf2f(v2.z) * w2 + bf2f(v3.z) * w3;
    a3 += bf2f(v0.w) * w0 + bf2f(v1.w) * w1 + bf2f(v2.w) * w2 + bf2f(v3.w) * w3;
  }
  for (; j < end; ++j) {
    int2 e0 = csre[j];
    ushort4 v0 = h4[(size_t)e0.x * 256 + fo4];
    float w0 = __int_as_float(e0.y);
    a0 += bf2f(v0.x) * w0; a1 += bf2f(v0.y) * w0;
    a2 += bf2f(v0.z) * w0; a3 += bf2f(v0.w) * w0;
  }
  ushort4 o;
  o.x = f2bf(a0); o.y = f2bf(a1); o.z = f2bf(a2); o.w = f2bf(a3);
  agg4[(size_t)i * 256 + fo4] = o;
}

// ---- mean pool of leaky(agg + bias); grid.z in [0,64): g = z>>5, b = z&31 ----
__global__ void k_pool(const unsigned short* __restrict__ agg_all,
                       const float* __restrict__ bias0, const float* __restrict__ bias1,
                       float* __restrict__ pooled_all) {
  int f = blockIdx.x * 256 + threadIdx.x;  // 0..1023
  int z = blockIdx.z;
  int g = z >> 5, b = z & 31;
  const unsigned short* agg = agg_all + (size_t)g * N_NODES * F_;
  const float* bias = g ? bias1 : bias0;
  float* pooled = pooled_all + (size_t)g * B_ * F_;
  int r0 = blockIdx.y * 100;
  float bf = bias[f];
  float s = 0.f;
  for (int r = 0; r < 100; ++r)
    s += leaky(bf2f(agg[(size_t)(b * NPG_ + r0 + r) * F_ + f]) + bf);
  atomicAdd(&pooled[b * F_ + f], s);
}

// ---- fc: coalesced w reads + LDS-staged pooled + wave shuffle-reduce ----
__global__ __launch_bounds__(256) void k_fc(const float* __restrict__ pooled_all,
                     const float* __restrict__ w0, const float* __restrict__ w1,
                     const float* __restrict__ bias0, const float* __restrict__ bias1,
                     float* __restrict__ out0, float* __restrict__ out1) {
  __shared__ float ps[F_];
  const int b = blockIdx.x, g = blockIdx.y, t = threadIdx.x;
  const float* p = pooled_all + (size_t)g * B_ * F_ + b * F_;
  const float* w = g ? w1 : w0;
  const float* bias = g ? bias1 : bias0;
  float* out = g ? out1 : out0;
  ((float4*)ps)[t] = ((const float4*)p)[t];   // 256*16B = 4KB = F_ floats
  __syncthreads();
  const int wave = t >> 6, lane = t & 63;
  for (int oo = 0; oo < 32; ++oo) {
    const int o = wave * 32 + oo;
    const float* wr = w + (size_t)o * F_;
    float a = 0.f;
#pragma unroll
    for (int c = 0; c < 16; ++c) a += wr[c * 64 + lane] * ps[c * 64 + lane];
#pragma unroll
    for (int m = 1; m < 64; m <<= 1) a += __shfl_xor(a, m, 64);
    if (lane == 0) out[b * OD_ + o] = leaky(a * (1.f / 500.f) + bias[o]);
  }
}

// ---- ragged pack ----
__global__ void k_pack(const float* __restrict__ m0, const float* __restrict__ m1,
                       const float* __restrict__ m2, const float* __restrict__ m3,
                       const int* __restrict__ l0, const int* __restrict__ l1,
                       const int* __restrict__ l2, const int* __restrict__ l3,
                       const float* __restrict__ rw, const float* __restrict__ rb,
                       float* __restrict__ seq) {
  __shared__ float xs[DD_];
  const int p = blockIdx.x, b = blockIdx.y, k = blockIdx.z;
  const float* mas = (k == 0) ? m0 : (k == 1) ? m1 : (k == 2) ? m2 : m3;
  const int*   lk  = (k == 0) ? l0 : (k == 1) ? l1 : (k == 2) ? l2 : l3;
  const int len = lk[b];
  if (p >= len) return;
  int off = 0;
  if (k > 0) off += l0[b];
  if (k > 1) off += l1[b];
  if (k > 2) off += l2[b];
  const int t = threadIdx.x;  // 64
  for (int d = t; d < DD_; d += 64) xs[d] = mas[(size_t)(b * LSUB_ + p) * DD_ + d];
  __syncthreads();
  if (t < TD_) {
    float v;
    if (t < TD_ - 2) {
      float a = rb[t];
      const float* w = &rw[t * DD_];
      for (int d = 0; d < DD_; ++d) a += xs[d] * w[d];
      v = a;
    } else if (t == TD_ - 2) {
      v = (k == 0 || k == 2) ? 1.f : 0.f;
    } else {
      v = (k < 2) ? 1.f : 0.f;
    }
    seq[((size_t)b * MAXLEN_ + off + p) * TD_ + t] = v;
  }
}

__global__ void k_totlen(const int* __restrict__ l0, const int* __restrict__ l1,
                         const int* __restrict__ l2, const int* __restrict__ l3,
                         int* __restrict__ tot) {
  int b = threadIdx.x;
  if (b < B_) tot[b] = l0[b] + l1[b] + l2[b] + l3[b];
}

// ---- qkv projection (skip dead rows) ----
__global__ void k_qkv(const float* __restrict__ xt, const float* __restrict__ w,
                      const float* __restrict__ bias, const int* __restrict__ tot,
                      float* __restrict__ qkv) {
  __shared__ float xs[TD_];
  const int row = blockIdx.x;
  if ((row & (MAXLEN_ - 1)) >= tot[row >> 9]) return;
  const int t = threadIdx.x;      // 128
  if (t < TD_) xs[t] = xt[(size_t)row * TD_ + t];
  __syncthreads();
  if (t < 3 * TD_) {
    float a = bias[t];
    const float* wr = &w[t * TD_];
#pragma unroll
    for (int k = 0; k < TD_; ++k) a += xs[k] * wr[k];
    qkv[(size_t)row * 96 + t] = a;
  }
}

// ---- attention: one lane-pair per query, single pass (scores |s|<~1) ----
__global__ __launch_bounds__(128) void k_attn(const float* __restrict__ qkv,
                                              const int* __restrict__ tot,
                                              float* __restrict__ obuf) {
  __shared__ float Kl[MAXLEN_ * DH_];
  __shared__ float Vl[MAXLEN_ * DH_];
  const int h = blockIdx.x, b = blockIdx.y, qz = blockIdx.z;
  const int t = threadIdx.x;  // 128
  const int L = tot[b];
  if (qz * 64 >= L) return;
  const float* base = &qkv[(size_t)b * MAXLEN_ * 96];
  for (int i = t; i < L * DH_; i += 128) {
    int p = i >> 3, d = i & 7;
    Kl[i] = base[p * 96 + 32 + h * 8 + d];
    Vl[i] = base[p * 96 + 64 + h * 8 + d];
  }
  __syncthreads();
  const int qi = qz * 64 + (t >> 1);
  if (qi >= L) return;
  const int half = t & 1;
  const float scale = 0.35355339059327373f;  // 1/sqrt(8)
  float q[8];
#pragma unroll
  for (int d = 0; d < 8; ++d) q[d] = base[qi * 96 + h * 8 + d] * scale;

  float l0 = 0.f, l1 = 0.f;
  float a0[8] = {0, 0, 0, 0, 0, 0, 0, 0};
  float a1[8] = {0, 0, 0, 0, 0, 0, 0, 0};
  int j = half;
  for (; j + 2 < L; j += 4) {
    const float* kr0 = &Kl[j * 8];
    const float* kr1 = &Kl[(j + 2) * 8];
    float s0 = 0.f, s1 = 0.f;
#pragma unroll
    for (int d = 0; d < 8; ++d) { s0 += q[d] * kr0[d]; s1 += q[d] * kr1[d]; }
    float p0 = __expf(s0), p1 = __expf(s1);
    l0 += p0; l1 += p1;
    const float* vr0 = &Vl[j * 8];
    const float* vr1 = &Vl[(j + 2) * 8];
#pragma unroll
    for (int d = 0; d < 8; ++d) { a0[d] += p0 * vr0[d]; a1[d] += p1 * vr1[d]; }
  }
  for (; j < L; j += 2) {
    const float* kr = &Kl[j * 8];
    float s = 0.f;
#pragma unroll
    for (int d = 0; d < 8; ++d) s += q[d] * kr[d];
    float p = __expf(s);
    l0 += p;
    const float* vr = &Vl[j * 8];
#pragma unroll
    for (int d = 0; d < 8; ++d) a0[d] += p * vr[d];
  }
  float l = l0 + l1;
#pragma unroll
  for (int d = 0; d < 8; ++d) a0[d] += a1[d];
  l += __shfl_xor(l, 1);
#pragma unroll
  for (int d = 0; d < 8; ++d) a0[d] += __shfl_xor(a0[d], 1);
  float inv = 1.f / l;
  const int dbase = half * 4;
  float4 o;
  o.x = a0[dbase + 0] * inv; o.y = a0[dbase + 1] * inv;
  o.z = a0[dbase + 2] * inv; o.w = a0[dbase + 3] * inv;
  *(float4*)&obuf[((size_t)b * MAXLEN_ + qi) * TD_ + h * 8 + dbase] = o;
}

// ---- fused post-attention: out-proj + residual + LN1 + FFN + residual + LN2 ----
__global__ __launch_bounds__(128) void k_post(const float* __restrict__ obuf,
                                              const float* __restrict__ ow,
                                              const float* __restrict__ ob,
                                              const float* __restrict__ l1w,
                                              const float* __restrict__ l1b,
                                              const float* __restrict__ f1w,
                                              const float* __restrict__ f1b,
                                              const float* __restrict__ f2w,
                                              const float* __restrict__ f2b,
                                              const float* __restrict__ l2w,
                                              const float* __restrict__ l2b,
                                              const int* __restrict__ tot,
                                              float* __restrict__ xt) {
  const int r = blockIdx.x, t = threadIdx.x;  // 128
  if ((r & (MAXLEN_ - 1)) >= tot[r >> 9]) return;
  __shared__ float xs[TD_];   // LN1 output
  __shared__ float hb[DFF_];
  if (t < TD_) {
    const float* orow = &obuf[(size_t)r * TD_];
    float a = ob[t] + xt[(size_t)r * TD_ + t];
    const float* wr = &ow[t * TD_];
#pragma unroll
    for (int k = 0; k < TD_; ++k) a += orow[k] * wr[k];
    float s1 = a, s2 = a * a;
#pragma unroll
    for (int m = 1; m < 32; m <<= 1) {
      s1 += __shfl_xor(s1, m, 32);
      s2 += __shfl_xor(s2, m, 32);
    }
    float mean = s1 * (1.f / 32.f);
    float var  = s2 * (1.f / 32.f) - mean * mean;
    xs[t] = (a - mean) * rsqrtf(var + EPS_) * l1w[t] + l1b[t];
  }
  __syncthreads();
  {
    float a = f1b[t];
    const float* wr = &f1w[t * TD_];
#pragma unroll
    for (int k = 0; k < TD_; ++k) a += xs[k] * wr[k];
    hb[t] = fmaxf(a, 0.f);
  }
  __syncthreads();
  if (t < TD_) {
    float a = f2b[t] + xs[t];
    const float* wr = &f2w[t * DFF_];
#pragma unroll
    for (int k = 0; k < DFF_; ++k) a += hb[k] * wr[k];
    float s1 = a, s2 = a * a;
#pragma unroll
    for (int m = 1; m < 32; m <<= 1) {
      s1 += __shfl_xor(s1, m, 32);
      s2 += __shfl_xor(s2, m, 32);
    }
    float mean = s1 * (1.f / 32.f);
    float var  = s2 * (1.f / 32.f) - mean * mean;
    xt[(size_t)r * TD_ + t] = (a - mean) * rsqrtf(var + EPS_) * l2w[t] + l2b[t];
  }
}

// ---- fused masked mean + final linear ----
__global__ __launch_bounds__(256) void k_maskfinal(const float* __restrict__ xt,
                                                   const int* __restrict__ tot,
                                                   const float* __restrict__ x1,
                                                   const float* __restrict__ x2,
                                                   const float* __restrict__ fw,
                                                   const float* __restrict__ fb,
                                                   float* __restrict__ out) {
  __shared__ float sbuf[8][32];
  __shared__ float mo[TD_];
  const int b = blockIdx.x, t = threadIdx.x;  // 256
  const int j = t & 31, c = t >> 5;
  const int L = tot[b];
  float s = 0.f;
  for (int p = c; p < L; p += 8) s += xt[((size_t)b * MAXLEN_ + p) * TD_ + j];
  sbuf[c][j] = s;
  __syncthreads();
  if (t < 32) {
    float a = 0.f;
#pragma unroll
    for (int cc = 0; cc < 8; ++cc) a += sbuf[cc][t];
    mo[t] = a / (float)L;
  }
  __syncthreads();
  if (t < 64) {
    float s2 = 0.f;
    for (int i = t; i < 2 * OD_ + TD_; i += 64) {
      float cv = (i < OD_) ? x1[b * OD_ + i]
               : (i < 2 * OD_) ? x2[b * OD_ + (i - OD_)]
               : mo[i - 2 * OD_];
      s2 += fw[i] * cv;
    }
#pragma unroll
    for (int m = 1; m < 64; m <<= 1) s2 += __shfl_xor(s2, m, 64);
    if (t == 0) out[b] = s2 + fb[0];
  }
}

extern "C" void kernel_launch(void* const* d_in, const int* in_sizes, int n_in,
                              void* d_out, int out_size, void* d_ws, size_t ws_size,
                              hipStream_t stream) {
  (void)in_sizes; (void)n_in; (void)out_size; (void)ws_size;
  const float* pro_x[2]  = {(const float*)d_in[0], (const float*)d_in[1]};
  const int*   pro_ei[2] = {(const int*)d_in[2], (const int*)d_in[3]};
  const float* mas[4]    = {(const float*)d_in[6], (const float*)d_in[8],
                            (const float*)d_in[10], (const float*)d_in[12]};
  const int*   lens[4]   = {(const int*)d_in[7], (const int*)d_in[9],
                            (const int*)d_in[11], (const int*)d_in[13]};
  const float* gw[2]  = {(const float*)d_in[14], (const float*)d_in[16]};
  const float* gb[2]  = {(const float*)d_in[15], (const float*)d_in[17]};
  const float* fcw[2] = {(const float*)d_in[18], (const float*)d_in[20]};
  const float* fcb[2] = {(const float*)d_in[19], (const float*)d_in[21]};
  const float* red_w = (const float*)d_in[22];
  const float* red_b = (const float*)d_in[23];
  const float* attn_in_w  = (const float*)d_in[24];
  const float* attn_in_b  = (const float*)d_in[25];
  const float* attn_out_w = (const float*)d_in[26];
  const float* attn_out_b = (const float*)d_in[27];
  const float* ln1_w = (const float*)d_in[28];
  const float* ln1_b = (const float*)d_in[29];
  const float* ln2_w = (const float*)d_in[30];
  const float* ln2_b = (const float*)d_in[31];
  const float* ff1_w = (const float*)d_in[32];
  const float* ff1_b = (const float*)d_in[33];
  const float* ff2_w = (const float*)d_in[34];
  const float* ff2_b = (const float*)d_in[35];
  const float* final_w = (const float*)d_in[36];
  const float* final_b = (const float*)d_in[37];
  float* out = (float*)d_out;

  char* p = (char*)d_ws;
  auto carve = [&](size_t bytes) -> void* {
    void* r = (void*)p;
    p += (bytes + 255) & ~(size_t)255;
    return r;
  };
  unsigned short* xb  = (unsigned short*)carve((size_t)2 * MPAD_ * F_ * 2);
  unsigned short* Wb  = (unsigned short*)carve((size_t)2 * F_ * F_ * 2);
  unsigned short* h   = (unsigned short*)carve((size_t)2 * MPAD_ * F_ * 2);
  unsigned short* agg = (unsigned short*)carve((size_t)2 * N_NODES * F_ * 2);
  int*   cnt      = (int*)carve((size_t)2 * N_NODES * 4);
  float* dinv     = (float*)carve((size_t)2 * N_NODES * 4);
  int*   rowstart = (int*)carve((size_t)2 * (N_NODES + 1) * 4);
  int*   cursor   = (int*)carve((size_t)2 * N_NODES * 4);
  int2*  csre     = (int2*)carve((size_t)2 * E_ * 8);
  float* pooled   = (float*)carve((size_t)2 * B_ * F_ * 4);
  float* xg[2];
  xg[0] = (float*)carve((size_t)B_ * OD_ * 4);
  xg[1] = (float*)carve((size_t)B_ * OD_ * 4);
  float* seq    = (float*)carve((size_t)B_ * MAXLEN_ * TD_ * 4);
  float* qkv    = (float*)carve((size_t)B_ * MAXLEN_ * 96 * 4);
  float* obuf   = (float*)carve((size_t)B_ * MAXLEN_ * TD_ * 4);
  int*   totlen = (int*)carve((size_t)B_ * 4);

  // ---- GCN branches (merged across both graphs) ----
  k_f2bf2<<<dim3(1024, 2), 256, 0, stream>>>(pro_x[0], pro_x[1], xb,
                                             xb + (size_t)MPAD_ * F_, (N_NODES * F_) / 4);
  k_f2bf2<<<dim3(512, 2), 256, 0, stream>>>(gw[0], gw[1], Wb, Wb + (size_t)F_ * F_,
                                            (F_ * F_) / 4);
  k_gemm256<<<dim3(252, 1, 2), 512, 0, stream>>>(xb, Wb, h);
  hipMemsetAsync(cnt, 0, (size_t)2 * N_NODES * 4, stream);
  k_hist<<<dim3(1000, 2), 256, 0, stream>>>(pro_ei[0], pro_ei[1], cnt, E_, N_NODES);
  k_scan<<<2, 256, 0, stream>>>(cnt, rowstart, cursor, dinv, N_NODES);
  k_scatter<<<dim3(1000, 2), 256, 0, stream>>>(pro_ei[0], pro_ei[1], dinv, cursor,
                                               csre, E_, N_NODES);
  k_gather<<<dim3(4, 4000, 2), 256, 0, stream>>>((const ushort4*)h, dinv, rowstart,
                                                 csre, (ushort4*)agg);
  hipMemsetAsync(pooled, 0, (size_t)2 * B_ * F_ * 4, stream);
  k_pool<<<dim3(4, 5, 64), 256, 0, stream>>>(agg, gb[0], gb[1], pooled);
  k_fc<<<dim3(B_, 2), 256, 0, stream>>>(pooled, fcw[0], fcw[1], fcb[0], fcb[1],
                                        xg[0], xg[1]);

  // ---- ragged pack (no memset: rows [0,tot) fully written; dead rows unread) ----
  k_pack<<<dim3(LSUB_, B_, 4), 64, 0, stream>>>(mas[0], mas[1], mas[2], mas[3],
                                                lens[0], lens[1], lens[2], lens[3],
                                                red_w, red_b, seq);
  k_totlen<<<1, 64, 0, stream>>>(lens[0], lens[1], lens[2], lens[3], totlen);

  // ---- transformer (2 layers) ----
  for (int li = 0; li < 2; ++li) {
    k_qkv<<<B_ * MAXLEN_, 128, 0, stream>>>(seq, attn_in_w + (size_t)li * 96 * TD_,
                                            attn_in_b + (size_t)li * 96, totlen, qkv);
    k_attn<<<dim3(NH_, B_, 8), 128, 0, stream>>>(qkv, totlen, obuf);
    k_post<<<B_ * MAXLEN_, 128, 0, stream>>>(
        obuf, attn_out_w + (size_t)li * TD_ * TD_, attn_out_b + (size_t)li * TD_,
        ln1_w + (size_t)li * TD_, ln1_b + (size_t)li * TD_,
        ff1_w + (size_t)li * DFF_ * TD_, ff1_b + (size_t)li * DFF_,
        ff2_w + (size_t)li * TD_ * DFF_, ff2_b + (size_t)li * TD_,
        ln2_w + (size_t)li * TD_, ln2_b + (size_t)li * TD_, totlen, seq);
  }

  // ---- fused masked mean + final ----
  k_maskfinal<<<B_, 256, 0, stream>>>(seq, totlen, xg[0], xg[1], final_w, final_b, out);
}

// Round 5
// 733.989 us; speedup vs baseline: 1.0809x; 1.0257x over previous
//
#include <hip/hip_runtime.h>
#include <stdint.h>

// ---- problem constants (from reference) ----
#define N_NODES 16000
#define MPAD_   16128   // N_NODES padded to multiple of 256 for the 256^2 GEMM
#define B_      32
#define NPG_    500
#define E_      256000
#define F_      1024
#define OD_     128
#define DD_     80
#define TD_     32
#define NH_     4
#define DH_     8
#define DFF_    128
#define LSUB_   128
#define MAXLEN_ 512
#define EPS_    1e-5f
#define SLOPE_  0.01f

typedef __bf16 bf16x8 __attribute__((ext_vector_type(8)));
typedef float  f32x4  __attribute__((ext_vector_type(4)));

__device__ __forceinline__ float leaky(float v) { return v >= 0.f ? v : SLOPE_ * v; }

__device__ __forceinline__ unsigned short f2bf(float f) {
  unsigned u = __float_as_uint(f);
  u += 0x7FFFu + ((u >> 16) & 1u);   // RNE
  return (unsigned short)(u >> 16);
}
__device__ __forceinline__ float bf2f(unsigned short u) {
  return __uint_as_float((unsigned)u << 16);
}
// packed-bf16 dword -> two floats (no ushort extraction)
__device__ __forceinline__ float bflo(unsigned u) { return __uint_as_float(u << 16); }
__device__ __forceinline__ float bfhi(unsigned u) { return __uint_as_float(u & 0xffff0000u); }
__device__ __forceinline__ unsigned pk2bf(float lo, float hi) {
  return (unsigned)f2bf(lo) | ((unsigned)f2bf(hi) << 16);
}

__device__ __forceinline__ void gld_lds16(const void* g, void* l) {
  __builtin_amdgcn_global_load_lds(
      (const __attribute__((address_space(1))) unsigned int*)g,
      (__attribute__((address_space(3))) unsigned int*)l, 16, 0, 0);
}

// ---- fp32 -> bf16 conversion for two tensors (grid.y selects) ----
__global__ void k_f2bf2(const float* __restrict__ in0, const float* __restrict__ in1,
                        unsigned short* __restrict__ out0, unsigned short* __restrict__ out1,
                        int n4) {
  const float* in = blockIdx.y ? in1 : in0;
  unsigned short* out = blockIdx.y ? out1 : out0;
  int i = blockIdx.x * blockDim.x + threadIdx.x;
  int stride = gridDim.x * blockDim.x;
  for (; i < n4; i += stride) {
    float4 v = ((const float4*)in)[i];
    ushort4 o;
    o.x = f2bf(v.x); o.y = f2bf(v.y); o.z = f2bf(v.z); o.w = f2bf(v.w);
    ((ushort4*)out)[i] = o;
  }
}

// ---- 256x256 8-phase bf16 MFMA GEMM: C[M,N] = A[M,K]*B[N,K]^T, bf16 out. ----
#define LDSA(bf, ks, row) (*(const bf16x8*)&lds[(bf)*16384 + (ks)*8192 + (row)*32 + rs])
#define LDSB(bf, ks, row) (*(const bf16x8*)&lds[32768 + (bf)*16384 + (ks)*8192 + (row)*32 + rs])
#define STG_A(bf, R, kti) do { \
  gld_lds16(&Ag[(size_t)(mBase + (R) + r4) * 1024 + (kti) * 64 + c4],      &lds[(bf)*16384 + (R)*32 + t*8]); \
  gld_lds16(&Ag[(size_t)(mBase + (R) + r4) * 1024 + (kti) * 64 + 32 + c4], &lds[(bf)*16384 + 8192 + (R)*32 + t*8]); \
} while (0)
#define STG_B(bf, R, kti) do { \
  gld_lds16(&Bg[(size_t)(nBase + (R) + r4) * 1024 + (kti) * 64 + c4],      &lds[32768 + (bf)*16384 + (R)*32 + t*8]); \
  gld_lds16(&Bg[(size_t)(nBase + (R) + r4) * 1024 + (kti) * 64 + 32 + c4], &lds[32768 + (bf)*16384 + 8192 + (R)*32 + t*8]); \
} while (0)
#define RD_Q0(bf) do { \
  _Pragma("unroll") for (int mi = 0; mi < 4; ++mi) \
  _Pragma("unroll") for (int ks = 0; ks < 2; ++ks) \
    aLo[mi][ks] = LDSA(bf, ks, wrow * 128 + mi * 16 + l15); \
  _Pragma("unroll") for (int ni = 0; ni < 2; ++ni) \
  _Pragma("unroll") for (int ks = 0; ks < 2; ++ks) \
    bLo[ni][ks] = LDSB(bf, ks, wcol * 64 + ni * 16 + l15); \
} while (0)
#define RD_BHI(bf) do { \
  _Pragma("unroll") for (int ni = 0; ni < 2; ++ni) \
  _Pragma("unroll") for (int ks = 0; ks < 2; ++ks) \
    bHi[ni][ks] = LDSB(bf, ks, wcol * 64 + (2 + ni) * 16 + l15); \
} while (0)
#define RD_AHI(bf) do { \
  _Pragma("unroll") for (int mi = 0; mi < 4; ++mi) \
  _Pragma("unroll") for (int ks = 0; ks < 2; ++ks) \
    aHi[mi][ks] = LDSA(bf, ks, wrow * 128 + (4 + mi) * 16 + l15); \
} while (0)
#define MM_Q0() do { __builtin_amdgcn_s_setprio(1); \
  _Pragma("unroll") for (int mi = 0; mi < 4; ++mi) \
  _Pragma("unroll") for (int ni = 0; ni < 2; ++ni) \
  _Pragma("unroll") for (int ks = 0; ks < 2; ++ks) \
    acc[mi][ni] = __builtin_amdgcn_mfma_f32_16x16x32_bf16(aLo[mi][ks], bLo[ni][ks], acc[mi][ni], 0, 0, 0); \
  __builtin_amdgcn_s_setprio(0); } while (0)
#define MM_Q1() do { __builtin_amdgcn_s_setprio(1); \
  _Pragma("unroll") for (int mi = 0; mi < 4; ++mi) \
  _Pragma("unroll") for (int ni = 0; ni < 2; ++ni) \
  _Pragma("unroll") for (int ks = 0; ks < 2; ++ks) \
    acc[mi][2 + ni] = __builtin_amdgcn_mfma_f32_16x16x32_bf16(aLo[mi][ks], bHi[ni][ks], acc[mi][2 + ni], 0, 0, 0); \
  __builtin_amdgcn_s_setprio(0); } while (0)
#define MM_Q3() do { __builtin_amdgcn_s_setprio(1); \
  _Pragma("unroll") for (int mi = 0; mi < 4; ++mi) \
  _Pragma("unroll") for (int ni = 0; ni < 2; ++ni) \
  _Pragma("unroll") for (int ks = 0; ks < 2; ++ks) \
    acc[4 + mi][2 + ni] = __builtin_amdgcn_mfma_f32_16x16x32_bf16(aHi[mi][ks], bHi[ni][ks], acc[4 + mi][2 + ni], 0, 0, 0); \
  __builtin_amdgcn_s_setprio(0); } while (0)
#define MM_Q2() do { __builtin_amdgcn_s_setprio(1); \
  _Pragma("unroll") for (int mi = 0; mi < 4; ++mi) \
  _Pragma("unroll") for (int ni = 0; ni < 2; ++ni) \
  _Pragma("unroll") for (int ks = 0; ks < 2; ++ks) \
    acc[4 + mi][ni] = __builtin_amdgcn_mfma_f32_16x16x32_bf16(aHi[mi][ks], bLo[ni][ks], acc[4 + mi][ni], 0, 0, 0); \
  __builtin_amdgcn_s_setprio(0); } while (0)
#define BAR() do { __builtin_amdgcn_sched_barrier(0); __builtin_amdgcn_s_barrier(); \
                   __builtin_amdgcn_sched_barrier(0); } while (0)
#define LGKM0() do { asm volatile("s_waitcnt lgkmcnt(0)" ::: "memory"); \
                     __builtin_amdgcn_sched_barrier(0); } while (0)
#define VM4() do { asm volatile("s_waitcnt vmcnt(4)" ::: "memory"); } while (0)
#define VM0() do { asm volatile("s_waitcnt vmcnt(0)" ::: "memory"); } while (0)

__global__ __launch_bounds__(512, 2) void k_gemm256(const unsigned short* __restrict__ Ag,
                                                    const unsigned short* __restrict__ Bg,
                                                    unsigned short* __restrict__ Cg) {
  __shared__ short lds[65536];   // 128 KiB: A [2][2][256][32] | B at +32768
  const int j  = blockIdx.x;     // 0..251
  const int x8 = j & 7;          // stable XCD id under round-robin dispatch
  const int chunk = (x8 < 4) ? x8 * 32 : 128 + (x8 - 4) * 31;  // bijective (m204)
  const int pos = chunk + (j >> 3);
  const int mb = pos >> 2, nb = pos & 3;   // nb fastest within XCD chunk
  const size_t g = blockIdx.z;
  Ag += g * (size_t)MPAD_ * 1024;
  Bg += g * (size_t)1024 * 1024;
  Cg += g * (size_t)MPAD_ * 1024;
  const int t = threadIdx.x;
  const int lane = t & 63, wave = t >> 6;
  const int wrow = wave >> 2, wcol = wave & 3;
  const int quad = lane >> 4, l15 = lane & 15;
  const int mBase = mb * 256, nBase = nb * 256;
  const int r4 = t >> 2;                                // 0..127 staging row
  const int c4 = (((t & 3) - ((t >> 3) & 3)) & 3) * 8;  // source chunk swizzle
  const int rs = ((quad + (l15 >> 1)) & 3) * 8;         // read slot swizzle

  f32x4 acc[8][4];
  f32x4 zero = {0.f, 0.f, 0.f, 0.f};
#pragma unroll
  for (int i = 0; i < 8; ++i)
#pragma unroll
    for (int jn = 0; jn < 4; ++jn) acc[i][jn] = zero;

  bf16x8 aLo[4][2], aHi[4][2], bLo[2][2], bHi[2][2];

  // prologue: T0 fully into buf0; B halves of T1 into buf1
  STG_A(0, 0, 0); STG_A(0, 128, 0); STG_B(0, 0, 0); STG_B(0, 128, 0);
  STG_B(1, 0, 1); STG_B(1, 128, 1);
  VM4();   // T0's 8 loads landed (leaves B(1) pair in flight)
  BAR();

  for (int kt = 0; kt < 16; kt += 2) {
    const bool s2 = (kt + 2) < 16;
    const bool s3 = (kt + 3) < 16;
    RD_Q0(0);
    STG_A(1, 0, kt + 1);
    BAR(); LGKM0(); MM_Q0(); BAR();
    RD_BHI(0);
    STG_A(1, 128, kt + 1);
    BAR(); LGKM0(); MM_Q1(); BAR();
    RD_AHI(0);
    if (s2) STG_B(0, 0, kt + 2);
    BAR(); LGKM0(); MM_Q3(); BAR();
    if (s2) { STG_B(0, 128, kt + 2); VM4(); } else VM0();
    BAR(); MM_Q2(); BAR();
    RD_Q0(1);
    if (s2) STG_A(0, 0, kt + 2);
    BAR(); LGKM0(); MM_Q0(); BAR();
    RD_BHI(1);
    if (s2) STG_A(0, 128, kt + 2);
    BAR(); LGKM0(); MM_Q1(); BAR();
    RD_AHI(1);
    if (s3) STG_B(1, 0, kt + 3);
    BAR(); LGKM0(); MM_Q3(); BAR();
    if (s3) { STG_B(1, 128, kt + 3); VM4(); }
    BAR(); MM_Q2(); BAR();
  }

#pragma unroll
  for (int mi = 0; mi < 8; ++mi)
#pragma unroll
    for (int ni = 0; ni < 4; ++ni)
#pragma unroll
      for (int r = 0; r < 4; ++r) {
        int grow = mBase + wrow * 128 + mi * 16 + quad * 4 + r;
        int gcol = nBase + wcol * 64 + ni * 16 + l15;
        Cg[(size_t)grow * 1024 + gcol] = f2bf(acc[mi][ni][r]);
      }
}

// ---- degree histogram over dst (grid.y = graph) ----
__global__ void k_hist(const int* __restrict__ ei0, const int* __restrict__ ei1,
                       int* __restrict__ cnt, int e, int n) {
  const int g = blockIdx.y;
  const int* dst = (g ? ei1 : ei0) + e;
  int i = blockIdx.x * 256 + threadIdx.x;
  if (i < e) atomicAdd(&cnt[g * n + dst[i]], 1);
}

// ---- per-graph block: exclusive scan of cnt -> rowstart/cursor; dinv = rsqrt(cnt+1) ----
__global__ void k_scan(const int* __restrict__ cnt_all, int* __restrict__ rowstart_all,
                       int* __restrict__ cursor_all, float* __restrict__ dinv_all, int n) {
  const int g = blockIdx.x;
  const int* cnt = cnt_all + g * n;
  int* rowstart = rowstart_all + g * (n + 1);
  int* cursor   = cursor_all + g * n;
  float* dinv   = dinv_all + g * n;
  __shared__ int part[256];
  __shared__ int base[257];
  int t = threadIdx.x;
  int chunk = (n + 255) >> 8;
  int s = 0;
  for (int j = 0; j < chunk; ++j) {
    int idx = t * chunk + j;
    if (idx < n) s += cnt[idx];
  }
  part[t] = s;
  __syncthreads();
  if (t == 0) {
    int a = 0;
    for (int i = 0; i < 256; ++i) { base[i] = a; a += part[i]; }
    base[256] = a;
  }
  __syncthreads();
  int a = base[t];
  for (int j = 0; j < chunk; ++j) {
    int idx = t * chunk + j;
    if (idx < n) {
      int c = cnt[idx];
      rowstart[idx] = a; cursor[idx] = a; a += c;
      dinv[idx] = rsqrtf((float)c + 1.0f);
    }
  }
  if (t == 0) rowstart[n] = base[256];
}

// ---- scatter edges to CSR, fused record {src, weight-bits} (grid.y = graph) ----
__global__ void k_scatter(const int* __restrict__ ei0, const int* __restrict__ ei1,
                          const float* __restrict__ dinv_all, int* __restrict__ cursor_all,
                          int2* __restrict__ csre_all, int e, int n) {
  const int g = blockIdx.y;
  const int* ei = g ? ei1 : ei0;
  int i = blockIdx.x * 256 + threadIdx.x;
  if (i < e) {
    int s = ei[i], d = ei[e + i];
    int p = atomicAdd(&cursor_all[g * n + d], 1);
    float w = dinv_all[g * n + s] * dinv_all[g * n + d];
    csre_all[(size_t)g * e + p] = make_int2(s, __float_as_int(w));
  }
}

// ---- sliced CSR gather v4: 8 slices (4.1 MB/XCD = L2-resident, per R3's 120MB
// fetch) x quarter-wave dst (16 lanes x uint4 = 128 feat/edge-visit).
// R4 post-mortem: 4-slice/8.2MB thrashed L2 (FETCH 120->317MB, serve-bound at
// 3.3TB/s). v4 keeps fat visits AND slice residency: 4 dst per wave, edge loop
// runs to max degree of the 4 quarters (Poisson(16): ~+26% iters), wave-iters
// ~1.37M vs R4's ~2.2M edge-visit-equivalents, ~7 VALU/edge.
// grid (8, 1000, 2): linear%8 == slice -> stable XCD. ----
__global__ __launch_bounds__(256) void k_gather(const uint4* __restrict__ h8_all,
                                                const float* __restrict__ dinv_all,
                                                const int* __restrict__ rowstart_all,
                                                const int2* __restrict__ csre_all,
                                                uint4* __restrict__ agg8_all) {
  const int g = blockIdx.z;
  const uint4* h8 = h8_all + (size_t)g * MPAD_ * 128;   // 128 uint4 per row
  const float* dinv = dinv_all + (size_t)g * N_NODES;
  const int* rowstart = rowstart_all + (size_t)g * (N_NODES + 1);
  const int2* csre = csre_all + (size_t)g * E_;
  uint4* agg8 = agg8_all + (size_t)g * N_NODES * 128;
  const int sl = blockIdx.x;                    // feature slice 0..7
  const int t = threadIdx.x;
  const int wv = t >> 6, lane = t & 63;
  const int qtr = lane >> 4, l16 = lane & 15;
  const int i = blockIdx.y * 16 + wv * 4 + qtr; // dst node (exactly 16000)
  const int fo8 = sl * 16 + l16;                // uint4 index within row
  const float di = dinv[i];
  const float selfw = di * di;
  uint4 sv = h8[(size_t)i * 128 + fo8];
  float a0 = bflo(sv.x) * selfw, a1 = bfhi(sv.x) * selfw;
  float a2 = bflo(sv.y) * selfw, a3 = bfhi(sv.y) * selfw;
  float a4 = bflo(sv.z) * selfw, a5 = bfhi(sv.z) * selfw;
  float a6 = bflo(sv.w) * selfw, a7 = bfhi(sv.w) * selfw;
  int j = rowstart[i];
  const int end = rowstart[i + 1];
  // unroll-2 for load ILP; per-lane bounds (quarters diverge via exec mask)
  for (; j + 2 <= end; j += 2) {
    int2 e0 = csre[j], e1 = csre[j + 1];
    uint4 v0 = h8[(size_t)e0.x * 128 + fo8];
    uint4 v1 = h8[(size_t)e1.x * 128 + fo8];
    float w0 = __int_as_float(e0.y), w1 = __int_as_float(e1.y);
    a0 += bflo(v0.x) * w0 + bflo(v1.x) * w1;
    a1 += bfhi(v0.x) * w0 + bfhi(v1.x) * w1;
    a2 += bflo(v0.y) * w0 + bflo(v1.y) * w1;
    a3 += bfhi(v0.y) * w0 + bfhi(v1.y) * w1;
    a4 += bflo(v0.z) * w0 + bflo(v1.z) * w1;
    a5 += bfhi(v0.z) * w0 + bfhi(v1.z) * w1;
    a6 += bflo(v0.w) * w0 + bflo(v1.w) * w1;
    a7 += bfhi(v0.w) * w0 + bfhi(v1.w) * w1;
  }
  if (j < end) {
    int2 e0 = csre[j];
    uint4 v0 = h8[(size_t)e0.x * 128 + fo8];
    float w0 = __int_as_float(e0.y);
    a0 += bflo(v0.x) * w0; a1 += bfhi(v0.x) * w0;
    a2 += bflo(v0.y) * w0; a3 += bfhi(v0.y) * w0;
    a4 += bflo(v0.z) * w0; a5 += bfhi(v0.z) * w0;
    a6 += bflo(v0.w) * w0; a7 += bfhi(v0.w) * w0;
  }
  uint4 o;
  o.x = pk2bf(a0, a1); o.y = pk2bf(a2, a3);
  o.z = pk2bf(a4, a5); o.w = pk2bf(a6, a7);
  agg8[(size_t)i * 128 + fo8] = o;
}

// ---- mean pool of leaky(agg + bias); grid.z in [0,64): g = z>>5, b = z&31 ----
__global__ void k_pool(const unsigned short* __restrict__ agg_all,
                       const float* __restrict__ bias0, const float* __restrict__ bias1,
                       float* __restrict__ pooled_all) {
  int f = blockIdx.x * 256 + threadIdx.x;  // 0..1023
  int z = blockIdx.z;
  int g = z >> 5, b = z & 31;
  const unsigned short* agg = agg_all + (size_t)g * N_NODES * F_;
  const float* bias = g ? bias1 : bias0;
  float* pooled = pooled_all + (size_t)g * B_ * F_;
  int r0 = blockIdx.y * 100;
  float bf = bias[f];
  float s = 0.f;
  for (int r = 0; r < 100; ++r)
    s += leaky(bf2f(agg[(size_t)(b * NPG_ + r0 + r) * F_ + f]) + bf);
  atomicAdd(&pooled[b * F_ + f], s);
}

// ---- fc: coalesced w reads + LDS-staged pooled + wave shuffle-reduce ----
__global__ __launch_bounds__(256) void k_fc(const float* __restrict__ pooled_all,
                     const float* __restrict__ w0, const float* __restrict__ w1,
                     const float* __restrict__ bias0, const float* __restrict__ bias1,
                     float* __restrict__ out0, float* __restrict__ out1) {
  __shared__ float ps[F_];
  const int b = blockIdx.x, g = blockIdx.y, t = threadIdx.x;
  const float* p = pooled_all + (size_t)g * B_ * F_ + b * F_;
  const float* w = g ? w1 : w0;
  const float* bias = g ? bias1 : bias0;
  float* out = g ? out1 : out0;
  ((float4*)ps)[t] = ((const float4*)p)[t];   // 256*16B = 4KB = F_ floats
  __syncthreads();
  const int wave = t >> 6, lane = t & 63;
  for (int oo = 0; oo < 32; ++oo) {
    const int o = wave * 32 + oo;
    const float* wr = w + (size_t)o * F_;
    float a = 0.f;
#pragma unroll
    for (int c = 0; c < 16; ++c) a += wr[c * 64 + lane] * ps[c * 64 + lane];
#pragma unroll
    for (int m = 1; m < 64; m <<= 1) a += __shfl_xor(a, m, 64);
    if (lane == 0) out[b * OD_ + o] = leaky(a * (1.f / 500.f) + bias[o]);
  }
}

// ---- ragged pack ----
__global__ void k_pack(const float* __restrict__ m0, const float* __restrict__ m1,
                       const float* __restrict__ m2, const float* __restrict__ m3,
                       const int* __restrict__ l0, const int* __restrict__ l1,
                       const int* __restrict__ l2, const int* __restrict__ l3,
                       const float* __restrict__ rw, const float* __restrict__ rb,
                       float* __restrict__ seq) {
  __shared__ float xs[DD_];
  const int p = blockIdx.x, b = blockIdx.y, k = blockIdx.z;
  const float* mas = (k == 0) ? m0 : (k == 1) ? m1 : (k == 2) ? m2 : m3;
  const int*   lk  = (k == 0) ? l0 : (k == 1) ? l1 : (k == 2) ? l2 : l3;
  const int len = lk[b];
  if (p >= len) return;
  int off = 0;
  if (k > 0) off += l0[b];
  if (k > 1) off += l1[b];
  if (k > 2) off += l2[b];
  const int t = threadIdx.x;  // 64
  for (int d = t; d < DD_; d += 64) xs[d] = mas[(size_t)(b * LSUB_ + p) * DD_ + d];
  __syncthreads();
  if (t < TD_) {
    float v;
    if (t < TD_ - 2) {
      float a = rb[t];
      const float* w = &rw[t * DD_];
      for (int d = 0; d < DD_; ++d) a += xs[d] * w[d];
      v = a;
    } else if (t == TD_ - 2) {
      v = (k == 0 || k == 2) ? 1.f : 0.f;
    } else {
      v = (k < 2) ? 1.f : 0.f;
    }
    seq[((size_t)b * MAXLEN_ + off + p) * TD_ + t] = v;
  }
}

__global__ void k_totlen(const int* __restrict__ l0, const int* __restrict__ l1,
                         const int* __restrict__ l2, const int* __restrict__ l3,
                         int* __restrict__ tot) {
  int b = threadIdx.x;
  if (b < B_) tot[b] = l0[b] + l1[b] + l2[b] + l3[b];
}

// ---- qkv projection (skip dead rows) ----
__global__ void k_qkv(const float* __restrict__ xt, const float* __restrict__ w,
                      const float* __restrict__ bias, const int* __restrict__ tot,
                      float* __restrict__ qkv) {
  __shared__ float xs[TD_];
  const int row = blockIdx.x;
  if ((row & (MAXLEN_ - 1)) >= tot[row >> 9]) return;
  const int t = threadIdx.x;      // 128
  if (t < TD_) xs[t] = xt[(size_t)row * TD_ + t];
  __syncthreads();
  if (t < 3 * TD_) {
    float a = bias[t];
    const float* wr = &w[t * TD_];
#pragma unroll
    for (int k = 0; k < TD_; ++k) a += xs[k] * wr[k];
    qkv[(size_t)row * 96 + t] = a;
  }
}

// ---- attention: one lane-pair per query, single pass (scores |s|<~1) ----
__global__ __launch_bounds__(128) void k_attn(const float* __restrict__ qkv,
                                              const int* __restrict__ tot,
                                              float* __restrict__ obuf) {
  __shared__ float Kl[MAXLEN_ * DH_];
  __shared__ float Vl[MAXLEN_ * DH_];
  const int h = blockIdx.x, b = blockIdx.y, qz = blockIdx.z;
  const int t = threadIdx.x;  // 128
  const int L = tot[b];
  if (qz * 64 >= L) return;
  const float* base = &qkv[(size_t)b * MAXLEN_ * 96];
  for (int i = t; i < L * DH_; i += 128) {
    int p = i >> 3, d = i & 7;
    Kl[i] = base[p * 96 + 32 + h * 8 + d];
    Vl[i] = base[p * 96 + 64 + h * 8 + d];
  }
  __syncthreads();
  const int qi = qz * 64 + (t >> 1);
  if (qi >= L) return;
  const int half = t & 1;
  const float scale = 0.35355339059327373f;  // 1/sqrt(8)
  float q[8];
#pragma unroll
  for (int d = 0; d < 8; ++d) q[d] = base[qi * 96 + h * 8 + d] * scale;

  float l0 = 0.f, l1 = 0.f;
  float a0[8] = {0, 0, 0, 0, 0, 0, 0, 0};
  float a1[8] = {0, 0, 0, 0, 0, 0, 0, 0};
  int j = half;
  for (; j + 2 < L; j += 4) {
    const float* kr0 = &Kl[j * 8];
    const float* kr1 = &Kl[(j + 2) * 8];
    float s0 = 0.f, s1 = 0.f;
#pragma unroll
    for (int d = 0; d < 8; ++d) { s0 += q[d] * kr0[d]; s1 += q[d] * kr1[d]; }
    float p0 = __expf(s0), p1 = __expf(s1);
    l0 += p0; l1 += p1;
    const float* vr0 = &Vl[j * 8];
    const float* vr1 = &Vl[(j + 2) * 8];
#pragma unroll
    for (int d = 0; d < 8; ++d) { a0[d] += p0 * vr0[d]; a1[d] += p1 * vr1[d]; }
  }
  for (; j < L; j += 2) {
    const float* kr = &Kl[j * 8];
    float s = 0.f;
#pragma unroll
    for (int d = 0; d < 8; ++d) s += q[d] * kr[d];
    float p = __expf(s);
    l0 += p;
    const float* vr = &Vl[j * 8];
#pragma unroll
    for (int d = 0; d < 8; ++d) a0[d] += p * vr[d];
  }
  float l = l0 + l1;
#pragma unroll
  for (int d = 0; d < 8; ++d) a0[d] += a1[d];
  l += __shfl_xor(l, 1);
#pragma unroll
  for (int d = 0; d < 8; ++d) a0[d] += __shfl_xor(a0[d], 1);
  float inv = 1.f / l;
  const int dbase = half * 4;
  float4 o;
  o.x = a0[dbase + 0] * inv; o.y = a0[dbase + 1] * inv;
  o.z = a0[dbase + 2] * inv; o.w = a0[dbase + 3] * inv;
  *(float4*)&obuf[((size_t)b * MAXLEN_ + qi) * TD_ + h * 8 + dbase] = o;
}

// ---- fused post-attention: out-proj + residual + LN1 + FFN + residual + LN2 ----
__global__ __launch_bounds__(128) void k_post(const float* __restrict__ obuf,
                                              const float* __restrict__ ow,
                                              const float* __restrict__ ob,
                                              const float* __restrict__ l1w,
                                              const float* __restrict__ l1b,
                                              const float* __restrict__ f1w,
                                              const float* __restrict__ f1b,
                                              const float* __restrict__ f2w,
                                              const float* __restrict__ f2b,
                                              const float* __restrict__ l2w,
                                              const float* __restrict__ l2b,
                                              const int* __restrict__ tot,
                                              float* __restrict__ xt) {
  const int r = blockIdx.x, t = threadIdx.x;  // 128
  if ((r & (MAXLEN_ - 1)) >= tot[r >> 9]) return;
  __shared__ float xs[TD_];   // LN1 output
  __shared__ float hb[DFF_];
  if (t < TD_) {
    const float* orow = &obuf[(size_t)r * TD_];
    float a = ob[t] + xt[(size_t)r * TD_ + t];
    const float* wr = &ow[t * TD_];
#pragma unroll
    for (int k = 0; k < TD_; ++k) a += orow[k] * wr[k];
    float s1 = a, s2 = a * a;
#pragma unroll
    for (int m = 1; m < 32; m <<= 1) {
      s1 += __shfl_xor(s1, m, 32);
      s2 += __shfl_xor(s2, m, 32);
    }
    float mean = s1 * (1.f / 32.f);
    float var  = s2 * (1.f / 32.f) - mean * mean;
    xs[t] = (a - mean) * rsqrtf(var + EPS_) * l1w[t] + l1b[t];
  }
  __syncthreads();
  {
    float a = f1b[t];
    const float* wr = &f1w[t * TD_];
#pragma unroll
    for (int k = 0; k < TD_; ++k) a += xs[k] * wr[k];
    hb[t] = fmaxf(a, 0.f);
  }
  __syncthreads();
  if (t < TD_) {
    float a = f2b[t] + xs[t];
    const float* wr = &f2w[t * DFF_];
#pragma unroll
    for (int k = 0; k < DFF_; ++k) a += hb[k] * wr[k];
    float s1 = a, s2 = a * a;
#pragma unroll
    for (int m = 1; m < 32; m <<= 1) {
      s1 += __shfl_xor(s1, m, 32);
      s2 += __shfl_xor(s2, m, 32);
    }
    float mean = s1 * (1.f / 32.f);
    float var  = s2 * (1.f / 32.f) - mean * mean;
    xt[(size_t)r * TD_ + t] = (a - mean) * rsqrtf(var + EPS_) * l2w[t] + l2b[t];
  }
}

// ---- fused masked mean + final linear ----
__global__ __launch_bounds__(256) void k_maskfinal(const float* __restrict__ xt,
                                                   const int* __restrict__ tot,
                                                   const float* __restrict__ x1,
                                                   const float* __restrict__ x2,
                                                   const float* __restrict__ fw,
                                                   const float* __restrict__ fb,
                                                   float* __restrict__ out) {
  __shared__ float sbuf[8][32];
  __shared__ float mo[TD_];
  const int b = blockIdx.x, t = threadIdx.x;  // 256
  const int j = t & 31, c = t >> 5;
  const int L = tot[b];
  float s = 0.f;
  for (int p = c; p < L; p += 8) s += xt[((size_t)b * MAXLEN_ + p) * TD_ + j];
  sbuf[c][j] = s;
  __syncthreads();
  if (t < 32) {
    float a = 0.f;
#pragma unroll
    for (int cc = 0; cc < 8; ++cc) a += sbuf[cc][t];
    mo[t] = a / (float)L;
  }
  __syncthreads();
  if (t < 64) {
    float s2 = 0.f;
    for (int i = t; i < 2 * OD_ + TD_; i += 64) {
      float cv = (i < OD_) ? x1[b * OD_ + i]
               : (i < 2 * OD_) ? x2[b * OD_ + (i - OD_)]
               : mo[i - 2 * OD_];
      s2 += fw[i] * cv;
    }
#pragma unroll
    for (int m = 1; m < 64; m <<= 1) s2 += __shfl_xor(s2, m, 64);
    if (t == 0) out[b] = s2 + fb[0];
  }
}

extern "C" void kernel_launch(void* const* d_in, const int* in_sizes, int n_in,
                              void* d_out, int out_size, void* d_ws, size_t ws_size,
                              hipStream_t stream) {
  (void)in_sizes; (void)n_in; (void)out_size; (void)ws_size;
  const float* pro_x[2]  = {(const float*)d_in[0], (const float*)d_in[1]};
  const int*   pro_ei[2] = {(const int*)d_in[2], (const int*)d_in[3]};
  const float* mas[4]    = {(const float*)d_in[6], (const float*)d_in[8],
                            (const float*)d_in[10], (const float*)d_in[12]};
  const int*   lens[4]   = {(const int*)d_in[7], (const int*)d_in[9],
                            (const int*)d_in[11], (const int*)d_in[13]};
  const float* gw[2]  = {(const float*)d_in[14], (const float*)d_in[16]};
  const float* gb[2]  = {(const float*)d_in[15], (const float*)d_in[17]};
  const float* fcw[2] = {(const float*)d_in[18], (const float*)d_in[20]};
  const float* fcb[2] = {(const float*)d_in[19], (const float*)d_in[21]};
  const float* red_w = (const float*)d_in[22];
  const float* red_b = (const float*)d_in[23];
  const float* attn_in_w  = (const float*)d_in[24];
  const float* attn_in_b  = (const float*)d_in[25];
  const float* attn_out_w = (const float*)d_in[26];
  const float* attn_out_b = (const float*)d_in[27];
  const float* ln1_w = (const float*)d_in[28];
  const float* ln1_b = (const float*)d_in[29];
  const float* ln2_w = (const float*)d_in[30];
  const float* ln2_b = (const float*)d_in[31];
  const float* ff1_w = (const float*)d_in[32];
  const float* ff1_b = (const float*)d_in[33];
  const float* ff2_w = (const float*)d_in[34];
  const float* ff2_b = (const float*)d_in[35];
  const float* final_w = (const float*)d_in[36];
  const float* final_b = (const float*)d_in[37];
  float* out = (float*)d_out;

  char* p = (char*)d_ws;
  auto carve = [&](size_t bytes) -> void* {
    void* r = (void*)p;
    p += (bytes + 255) & ~(size_t)255;
    return r;
  };
  unsigned short* xb  = (unsigned short*)carve((size_t)2 * MPAD_ * F_ * 2);
  unsigned short* Wb  = (unsigned short*)carve((size_t)2 * F_ * F_ * 2);
  unsigned short* h   = (unsigned short*)carve((size_t)2 * MPAD_ * F_ * 2);
  unsigned short* agg = (unsigned short*)carve((size_t)2 * N_NODES * F_ * 2);
  int*   cnt      = (int*)carve((size_t)2 * N_NODES * 4);
  float* dinv     = (float*)carve((size_t)2 * N_NODES * 4);
  int*   rowstart = (int*)carve((size_t)2 * (N_NODES + 1) * 4);
  int*   cursor   = (int*)carve((size_t)2 * N_NODES * 4);
  int2*  csre     = (int2*)carve((size_t)2 * E_ * 8);
  float* pooled   = (float*)carve((size_t)2 * B_ * F_ * 4);
  float* xg[2];
  xg[0] = (float*)carve((size_t)B_ * OD_ * 4);
  xg[1] = (float*)carve((size_t)B_ * OD_ * 4);
  float* seq    = (float*)carve((size_t)B_ * MAXLEN_ * TD_ * 4);
  float* qkv    = (float*)carve((size_t)B_ * MAXLEN_ * 96 * 4);
  float* obuf   = (float*)carve((size_t)B_ * MAXLEN_ * TD_ * 4);
  int*   totlen = (int*)carve((size_t)B_ * 4);

  // ---- GCN branches (merged across both graphs) ----
  k_f2bf2<<<dim3(1024, 2), 256, 0, stream>>>(pro_x[0], pro_x[1], xb,
                                             xb + (size_t)MPAD_ * F_, (N_NODES * F_) / 4);
  k_f2bf2<<<dim3(512, 2), 256, 0, stream>>>(gw[0], gw[1], Wb, Wb + (size_t)F_ * F_,
                                            (F_ * F_) / 4);
  k_gemm256<<<dim3(252, 1, 2), 512, 0, stream>>>(xb, Wb, h);
  hipMemsetAsync(cnt, 0, (size_t)2 * N_NODES * 4, stream);
  k_hist<<<dim3(1000, 2), 256, 0, stream>>>(pro_ei[0], pro_ei[1], cnt, E_, N_NODES);
  k_scan<<<2, 256, 0, stream>>>(cnt, rowstart, cursor, dinv, N_NODES);
  k_scatter<<<dim3(1000, 2), 256, 0, stream>>>(pro_ei[0], pro_ei[1], dinv, cursor,
                                               csre, E_, N_NODES);
  k_gather<<<dim3(8, 1000, 2), 256, 0, stream>>>((const uint4*)h, dinv, rowstart,
                                                 csre, (uint4*)agg);
  hipMemsetAsync(pooled, 0, (size_t)2 * B_ * F_ * 4, stream);
  k_pool<<<dim3(4, 5, 64), 256, 0, stream>>>(agg, gb[0], gb[1], pooled);
  k_fc<<<dim3(B_, 2), 256, 0, stream>>>(pooled, fcw[0], fcw[1], fcb[0], fcb[1],
                                        xg[0], xg[1]);

  // ---- ragged pack (no memset: rows [0,tot) fully written; dead rows unread) ----
  k_pack<<<dim3(LSUB_, B_, 4), 64, 0, stream>>>(mas[0], mas[1], mas[2], mas[3],
                                                lens[0], lens[1], lens[2], lens[3],
                                                red_w, red_b, seq);
  k_totlen<<<1, 64, 0, stream>>>(lens[0], lens[1], lens[2], lens[3], totlen);

  // ---- transformer (2 layers) ----
  for (int li = 0; li < 2; ++li) {
    k_qkv<<<B_ * MAXLEN_, 128, 0, stream>>>(seq, attn_in_w + (size_t)li * 96 * TD_,
                                            attn_in_b + (size_t)li * 96, totlen, qkv);
    k_attn<<<dim3(NH_, B_, 8), 128, 0, stream>>>(qkv, totlen, obuf);
    k_post<<<B_ * MAXLEN_, 128, 0, stream>>>(
        obuf, attn_out_w + (size_t)li * TD_ * TD_, attn_out_b + (size_t)li * TD_,
        ln1_w + (size_t)li * TD_, ln1_b + (size_t)li * TD_,
        ff1_w + (size_t)li * DFF_ * TD_, ff1_b + (size_t)li * DFF_,
        ff2_w + (size_t)li * TD_ * DFF_, ff2_b + (size_t)li * TD_,
        ln2_w + (size_t)li * TD_, ln2_b + (size_t)li * TD_, totlen, seq);
  }

  // ---- fused masked mean + final ----
  k_maskfinal<<<B_, 256, 0, stream>>>(seq, totlen, xg[0], xg[1], final_w, final_b, out);
}

// Round 7
// 721.203 us; speedup vs baseline: 1.1000x; 1.0177x over previous
//
#include <hip/hip_runtime.h>
#include <stdint.h>

// ---- problem constants (from reference) ----
#define N_NODES 16000
#define MPAD_   16128   // N_NODES padded to multiple of 256 for the 256^2 GEMM
#define B_      32
#define NPG_    500
#define E_      256000
#define F_      1024
#define OD_     128
#define DD_     80
#define TD_     32
#define NH_     4
#define DH_     8
#define DFF_    128
#define LSUB_   128
#define MAXLEN_ 512
#define EPS_    1e-5f
#define SLOPE_  0.01f

typedef __bf16 bf16x8 __attribute__((ext_vector_type(8)));
typedef float  f32x4  __attribute__((ext_vector_type(4)));
typedef unsigned u32x4 __attribute__((ext_vector_type(4)));  // native vec for nt-store

__device__ __forceinline__ float leaky(float v) { return v >= 0.f ? v : SLOPE_ * v; }

__device__ __forceinline__ unsigned short f2bf(float f) {
  unsigned u = __float_as_uint(f);
  u += 0x7FFFu + ((u >> 16) & 1u);   // RNE
  return (unsigned short)(u >> 16);
}
__device__ __forceinline__ float bf2f(unsigned short u) {
  return __uint_as_float((unsigned)u << 16);
}
// packed-bf16 dword -> two floats (no ushort extraction)
__device__ __forceinline__ float bflo(unsigned u) { return __uint_as_float(u << 16); }
__device__ __forceinline__ float bfhi(unsigned u) { return __uint_as_float(u & 0xffff0000u); }
__device__ __forceinline__ unsigned pk2bf(float lo, float hi) {
  return (unsigned)f2bf(lo) | ((unsigned)f2bf(hi) << 16);
}

__device__ __forceinline__ void gld_lds16(const void* g, void* l) {
  __builtin_amdgcn_global_load_lds(
      (const __attribute__((address_space(1))) unsigned int*)g,
      (__attribute__((address_space(3))) unsigned int*)l, 16, 0, 0);
}

// ---- prep: fp32->bf16 for {x0,x1,w0,w1} + zero cnt; grid (1024, 5) ----
__global__ void k_prep(const float* __restrict__ x0, const float* __restrict__ x1,
                       const float* __restrict__ w0, const float* __restrict__ w1,
                       unsigned short* __restrict__ xb0, unsigned short* __restrict__ xb1,
                       unsigned short* __restrict__ wb0, unsigned short* __restrict__ wb1,
                       int* __restrict__ cnt) {
  const int y = blockIdx.y;
  int i = blockIdx.x * 256 + threadIdx.x;
  const int stride = gridDim.x * 256;
  if (y == 4) {
    int4 z = make_int4(0, 0, 0, 0);
    for (; i < (2 * N_NODES) / 4; i += stride) ((int4*)cnt)[i] = z;
    return;
  }
  const float* in = (y == 0) ? x0 : (y == 1) ? x1 : (y == 2) ? w0 : w1;
  unsigned short* out = (y == 0) ? xb0 : (y == 1) ? xb1 : (y == 2) ? wb0 : wb1;
  const int n4 = (y < 2) ? (N_NODES * F_ / 4) : (F_ * F_ / 4);
  for (; i < n4; i += stride) {
    float4 v = ((const float4*)in)[i];
    ushort4 o;
    o.x = f2bf(v.x); o.y = f2bf(v.y); o.z = f2bf(v.z); o.w = f2bf(v.w);
    ((ushort4*)out)[i] = o;
  }
}

// ---- 256x256 8-phase bf16 MFMA GEMM: C[M,N] = A[M,K]*B[N,K]^T, bf16 out. ----
#define LDSA(bf, ks, row) (*(const bf16x8*)&lds[(bf)*16384 + (ks)*8192 + (row)*32 + rs])
#define LDSB(bf, ks, row) (*(const bf16x8*)&lds[32768 + (bf)*16384 + (ks)*8192 + (row)*32 + rs])
#define STG_A(bf, R, kti) do { \
  gld_lds16(&Ag[(size_t)(mBase + (R) + r4) * 1024 + (kti) * 64 + c4],      &lds[(bf)*16384 + (R)*32 + t*8]); \
  gld_lds16(&Ag[(size_t)(mBase + (R) + r4) * 1024 + (kti) * 64 + 32 + c4], &lds[(bf)*16384 + 8192 + (R)*32 + t*8]); \
} while (0)
#define STG_B(bf, R, kti) do { \
  gld_lds16(&Bg[(size_t)(nBase + (R) + r4) * 1024 + (kti) * 64 + c4],      &lds[32768 + (bf)*16384 + (R)*32 + t*8]); \
  gld_lds16(&Bg[(size_t)(nBase + (R) + r4) * 1024 + (kti) * 64 + 32 + c4], &lds[32768 + (bf)*16384 + 8192 + (R)*32 + t*8]); \
} while (0)
#define RD_Q0(bf) do { \
  _Pragma("unroll") for (int mi = 0; mi < 4; ++mi) \
  _Pragma("unroll") for (int ks = 0; ks < 2; ++ks) \
    aLo[mi][ks] = LDSA(bf, ks, wrow * 128 + mi * 16 + l15); \
  _Pragma("unroll") for (int ni = 0; ni < 2; ++ni) \
  _Pragma("unroll") for (int ks = 0; ks < 2; ++ks) \
    bLo[ni][ks] = LDSB(bf, ks, wcol * 64 + ni * 16 + l15); \
} while (0)
#define RD_BHI(bf) do { \
  _Pragma("unroll") for (int ni = 0; ni < 2; ++ni) \
  _Pragma("unroll") for (int ks = 0; ks < 2; ++ks) \
    bHi[ni][ks] = LDSB(bf, ks, wcol * 64 + (2 + ni) * 16 + l15); \
} while (0)
#define RD_AHI(bf) do { \
  _Pragma("unroll") for (int mi = 0; mi < 4; ++mi) \
  _Pragma("unroll") for (int ks = 0; ks < 2; ++ks) \
    aHi[mi][ks] = LDSA(bf, ks, wrow * 128 + (4 + mi) * 16 + l15); \
} while (0)
#define MM_Q0() do { __builtin_amdgcn_s_setprio(1); \
  _Pragma("unroll") for (int mi = 0; mi < 4; ++mi) \
  _Pragma("unroll") for (int ni = 0; ni < 2; ++ni) \
  _Pragma("unroll") for (int ks = 0; ks < 2; ++ks) \
    acc[mi][ni] = __builtin_amdgcn_mfma_f32_16x16x32_bf16(aLo[mi][ks], bLo[ni][ks], acc[mi][ni], 0, 0, 0); \
  __builtin_amdgcn_s_setprio(0); } while (0)
#define MM_Q1() do { __builtin_amdgcn_s_setprio(1); \
  _Pragma("unroll") for (int mi = 0; mi < 4; ++mi) \
  _Pragma("unroll") for (int ni = 0; ni < 2; ++ni) \
  _Pragma("unroll") for (int ks = 0; ks < 2; ++ks) \
    acc[mi][2 + ni] = __builtin_amdgcn_mfma_f32_16x16x32_bf16(aLo[mi][ks], bHi[ni][ks], acc[mi][2 + ni], 0, 0, 0); \
  __builtin_amdgcn_s_setprio(0); } while (0)
#define MM_Q3() do { __builtin_amdgcn_s_setprio(1); \
  _Pragma("unroll") for (int mi = 0; mi < 4; ++mi) \
  _Pragma("unroll") for (int ni = 0; ni < 2; ++ni) \
  _Pragma("unroll") for (int ks = 0; ks < 2; ++ks) \
    acc[4 + mi][2 + ni] = __builtin_amdgcn_mfma_f32_16x16x32_bf16(aHi[mi][ks], bHi[ni][ks], acc[4 + mi][2 + ni], 0, 0, 0); \
  __builtin_amdgcn_s_setprio(0); } while (0)
#define MM_Q2() do { __builtin_amdgcn_s_setprio(1); \
  _Pragma("unroll") for (int mi = 0; mi < 4; ++mi) \
  _Pragma("unroll") for (int ni = 0; ni < 2; ++ni) \
  _Pragma("unroll") for (int ks = 0; ks < 2; ++ks) \
    acc[4 + mi][ni] = __builtin_amdgcn_mfma_f32_16x16x32_bf16(aHi[mi][ks], bLo[ni][ks], acc[4 + mi][ni], 0, 0, 0); \
  __builtin_amdgcn_s_setprio(0); } while (0)
#define BAR() do { __builtin_amdgcn_sched_barrier(0); __builtin_amdgcn_s_barrier(); \
                   __builtin_amdgcn_sched_barrier(0); } while (0)
#define LGKM0() do { asm volatile("s_waitcnt lgkmcnt(0)" ::: "memory"); \
                     __builtin_amdgcn_sched_barrier(0); } while (0)
#define VM4() do { asm volatile("s_waitcnt vmcnt(4)" ::: "memory"); } while (0)
#define VM0() do { asm volatile("s_waitcnt vmcnt(0)" ::: "memory"); } while (0)

__global__ __launch_bounds__(512, 2) void k_gemm256(const unsigned short* __restrict__ Ag,
                                                    const unsigned short* __restrict__ Bg,
                                                    unsigned short* __restrict__ Cg) {
  __shared__ short lds[65536];   // 128 KiB: A [2][2][256][32] | B at +32768
  const int j  = blockIdx.x;     // 0..251
  const int x8 = j & 7;          // stable XCD id under round-robin dispatch
  const int chunk = (x8 < 4) ? x8 * 32 : 128 + (x8 - 4) * 31;  // bijective (m204)
  const int pos = chunk + (j >> 3);
  const int mb = pos >> 2, nb = pos & 3;   // nb fastest within XCD chunk
  const size_t g = blockIdx.z;
  Ag += g * (size_t)MPAD_ * 1024;
  Bg += g * (size_t)1024 * 1024;
  Cg += g * (size_t)MPAD_ * 1024;
  const int t = threadIdx.x;
  const int lane = t & 63, wave = t >> 6;
  const int wrow = wave >> 2, wcol = wave & 3;
  const int quad = lane >> 4, l15 = lane & 15;
  const int mBase = mb * 256, nBase = nb * 256;
  const int r4 = t >> 2;                                // 0..127 staging row
  const int c4 = (((t & 3) - ((t >> 3) & 3)) & 3) * 8;  // source chunk swizzle
  const int rs = ((quad + (l15 >> 1)) & 3) * 8;         // read slot swizzle

  f32x4 acc[8][4];
  f32x4 zero = {0.f, 0.f, 0.f, 0.f};
#pragma unroll
  for (int i = 0; i < 8; ++i)
#pragma unroll
    for (int jn = 0; jn < 4; ++jn) acc[i][jn] = zero;

  bf16x8 aLo[4][2], aHi[4][2], bLo[2][2], bHi[2][2];

  // prologue: T0 fully into buf0; B halves of T1 into buf1
  STG_A(0, 0, 0); STG_A(0, 128, 0); STG_B(0, 0, 0); STG_B(0, 128, 0);
  STG_B(1, 0, 1); STG_B(1, 128, 1);
  VM4();   // T0's 8 loads landed (leaves B(1) pair in flight)
  BAR();

  for (int kt = 0; kt < 16; kt += 2) {
    const bool s2 = (kt + 2) < 16;
    const bool s3 = (kt + 3) < 16;
    RD_Q0(0);
    STG_A(1, 0, kt + 1);
    BAR(); LGKM0(); MM_Q0(); BAR();
    RD_BHI(0);
    STG_A(1, 128, kt + 1);
    BAR(); LGKM0(); MM_Q1(); BAR();
    RD_AHI(0);
    if (s2) STG_B(0, 0, kt + 2);
    BAR(); LGKM0(); MM_Q3(); BAR();
    if (s2) { STG_B(0, 128, kt + 2); VM4(); } else VM0();
    BAR(); MM_Q2(); BAR();
    RD_Q0(1);
    if (s2) STG_A(0, 0, kt + 2);
    BAR(); LGKM0(); MM_Q0(); BAR();
    RD_BHI(1);
    if (s2) STG_A(0, 128, kt + 2);
    BAR(); LGKM0(); MM_Q1(); BAR();
    RD_AHI(1);
    if (s3) STG_B(1, 0, kt + 3);
    BAR(); LGKM0(); MM_Q3(); BAR();
    if (s3) { STG_B(1, 128, kt + 3); VM4(); }
    BAR(); MM_Q2(); BAR();
  }

#pragma unroll
  for (int mi = 0; mi < 8; ++mi)
#pragma unroll
    for (int ni = 0; ni < 4; ++ni)
#pragma unroll
      for (int r = 0; r < 4; ++r) {
        int grow = mBase + wrow * 128 + mi * 16 + quad * 4 + r;
        int gcol = nBase + wcol * 64 + ni * 16 + l15;
        Cg[(size_t)grow * 1024 + gcol] = f2bf(acc[mi][ni][r]);
      }
}

// ---- degree histogram over dst (grid.y = graph) ----
__global__ void k_hist(const int* __restrict__ ei0, const int* __restrict__ ei1,
                       int* __restrict__ cnt, int e, int n) {
  const int g = blockIdx.y;
  const int* dst = (g ? ei1 : ei0) + e;
  int i = blockIdx.x * 256 + threadIdx.x;
  if (i < e) atomicAdd(&cnt[g * n + dst[i]], 1);
}

// ---- per-graph block: exclusive scan of cnt -> rowstart/cursor; dinv = rsqrt(cnt+1) ----
__global__ void k_scan(const int* __restrict__ cnt_all, int* __restrict__ rowstart_all,
                       int* __restrict__ cursor_all, float* __restrict__ dinv_all, int n) {
  const int g = blockIdx.x;
  const int* cnt = cnt_all + g * n;
  int* rowstart = rowstart_all + g * (n + 1);
  int* cursor   = cursor_all + g * n;
  float* dinv   = dinv_all + g * n;
  __shared__ int part[256];
  __shared__ int base[257];
  int t = threadIdx.x;
  int chunk = (n + 255) >> 8;
  int s = 0;
  for (int j = 0; j < chunk; ++j) {
    int idx = t * chunk + j;
    if (idx < n) s += cnt[idx];
  }
  part[t] = s;
  __syncthreads();
  if (t == 0) {
    int a = 0;
    for (int i = 0; i < 256; ++i) { base[i] = a; a += part[i]; }
    base[256] = a;
  }
  __syncthreads();
  int a = base[t];
  for (int j = 0; j < chunk; ++j) {
    int idx = t * chunk + j;
    if (idx < n) {
      int c = cnt[idx];
      rowstart[idx] = a; cursor[idx] = a; a += c;
      dinv[idx] = rsqrtf((float)c + 1.0f);
    }
  }
  if (t == 0) rowstart[n] = base[256];
}

// ---- scatter edges to CSR, fused record {src, weight-bits} (grid.y = graph) ----
__global__ void k_scatter(const int* __restrict__ ei0, const int* __restrict__ ei1,
                          const float* __restrict__ dinv_all, int* __restrict__ cursor_all,
                          int2* __restrict__ csre_all, int e, int n) {
  const int g = blockIdx.y;
  const int* ei = g ? ei1 : ei0;
  int i = blockIdx.x * 256 + threadIdx.x;
  if (i < e) {
    int s = ei[i], d = ei[e + i];
    int p = atomicAdd(&cursor_all[g * n + d], 1);
    float w = dinv_all[g * n + s] * dinv_all[g * n + d];
    csre_all[(size_t)g * e + p] = make_int2(s, __float_as_int(w));
  }
}

// ---- sliced CSR gather v5: v4 structure + SLICE-MAJOR agg layout + nt stores.
// R5 post-mortem: FETCH 148 vs ~101 ideal = RFO write-allocate (each 128B agg
// line written 16B-at-a-time by 8 different XCDs) + agg evicting the h slice.
// v5: agg_s[g][slice][node][128feat] -> each quarter writes 256B contiguous
// full lines from one XCD; nontemporal store keeps the 64MB agg stream out of
// L2 (h slice 4.1MB stays resident). grid (8, 1000, 2). ----
__global__ __launch_bounds__(256) void k_gather(const uint4* __restrict__ h8_all,
                                                const float* __restrict__ dinv_all,
                                                const int* __restrict__ rowstart_all,
                                                const int2* __restrict__ csre_all,
                                                unsigned* __restrict__ aggs_all) {
  const int g = blockIdx.z;
  const uint4* h8 = h8_all + (size_t)g * MPAD_ * 128;   // 128 uint4 per row
  const float* dinv = dinv_all + (size_t)g * N_NODES;
  const int* rowstart = rowstart_all + (size_t)g * (N_NODES + 1);
  const int2* csre = csre_all + (size_t)g * E_;
  const int sl = blockIdx.x;                    // feature slice 0..7
  const int t = threadIdx.x;
  const int wv = t >> 6, lane = t & 63;
  const int qtr = lane >> 4, l16 = lane & 15;
  const int i = blockIdx.y * 16 + wv * 4 + qtr; // dst node (exactly 16000)
  const int fo8 = sl * 16 + l16;                // uint4 index within row
  const float di = dinv[i];
  const float selfw = di * di;
  uint4 sv = h8[(size_t)i * 128 + fo8];
  float a0 = bflo(sv.x) * selfw, a1 = bfhi(sv.x) * selfw;
  float a2 = bflo(sv.y) * selfw, a3 = bfhi(sv.y) * selfw;
  float a4 = bflo(sv.z) * selfw, a5 = bfhi(sv.z) * selfw;
  float a6 = bflo(sv.w) * selfw, a7 = bfhi(sv.w) * selfw;
  int j = rowstart[i];
  const int end = rowstart[i + 1];
  for (; j + 2 <= end; j += 2) {
    int2 e0 = csre[j], e1 = csre[j + 1];
    uint4 v0 = h8[(size_t)e0.x * 128 + fo8];
    uint4 v1 = h8[(size_t)e1.x * 128 + fo8];
    float w0 = __int_as_float(e0.y), w1 = __int_as_float(e1.y);
    a0 += bflo(v0.x) * w0 + bflo(v1.x) * w1;
    a1 += bfhi(v0.x) * w0 + bfhi(v1.x) * w1;
    a2 += bflo(v0.y) * w0 + bflo(v1.y) * w1;
    a3 += bfhi(v0.y) * w0 + bfhi(v1.y) * w1;
    a4 += bflo(v0.z) * w0 + bflo(v1.z) * w1;
    a5 += bfhi(v0.z) * w0 + bfhi(v1.z) * w1;
    a6 += bflo(v0.w) * w0 + bflo(v1.w) * w1;
    a7 += bfhi(v0.w) * w0 + bfhi(v1.w) * w1;
  }
  if (j < end) {
    int2 e0 = csre[j];
    uint4 v0 = h8[(size_t)e0.x * 128 + fo8];
    float w0 = __int_as_float(e0.y);
    a0 += bflo(v0.x) * w0; a1 += bfhi(v0.x) * w0;
    a2 += bflo(v0.y) * w0; a3 += bfhi(v0.y) * w0;
    a4 += bflo(v0.z) * w0; a5 += bfhi(v0.z) * w0;
    a6 += bflo(v0.w) * w0; a7 += bfhi(v0.w) * w0;
  }
  u32x4 o;
  o.x = pk2bf(a0, a1); o.y = pk2bf(a2, a3);
  o.z = pk2bf(a4, a5); o.w = pk2bf(a6, a7);
  u32x4* dst = (u32x4*)&aggs_all[(((size_t)(g * 8 + sl) * N_NODES + i) * 16 + l16) * 4];
  __builtin_nontemporal_store(o, dst);
}

// ---- pool partial sums: grid (B, 2, 5), 512 thr; no atomics/memset.
// agg_s slice-major layout; thread t covers feats {2t, 2t+1}:
// sl = t>>6, ushort2 offset o = t&63, bias idx = 2t. ----
__global__ __launch_bounds__(512) void k_poolpart(const unsigned short* __restrict__ aggs,
                                                  const float* __restrict__ bias0,
                                                  const float* __restrict__ bias1,
                                                  float* __restrict__ partial) {
  const int b = blockIdx.x, g = blockIdx.y, c = blockIdx.z;
  const int t = threadIdx.x;
  const int sl = t >> 6, o = t & 63;
  const float* bias = g ? bias1 : bias0;
  const float bf0 = bias[t * 2], bf1 = bias[t * 2 + 1];
  const ushort2* base = (const ushort2*)aggs + ((size_t)(g * 8 + sl) * N_NODES) * 64 + o;
  const int r0 = b * NPG_ + c * 100;
  float s0 = 0.f, s1 = 0.f;
  for (int r = 0; r < 100; ++r) {
    ushort2 v = base[(size_t)(r0 + r) * 64];
    s0 += leaky(bf2f(v.x) + bf0);
    s1 += leaky(bf2f(v.y) + bf1);
  }
  *(float2*)&partial[(((size_t)c * 2 + g) * B_ + b) * F_ + t * 2] = make_float2(s0, s1);
}

// ---- fc: sum 5 partials in-reg -> LDS, coalesced w + wave shuffle-reduce ----
__global__ __launch_bounds__(256) void k_fc(const float* __restrict__ partial,
                     const float* __restrict__ w0, const float* __restrict__ w1,
                     const float* __restrict__ bias0, const float* __restrict__ bias1,
                     float* __restrict__ out0, float* __restrict__ out1) {
  __shared__ float ps[F_];
  const int b = blockIdx.x, g = blockIdx.y, t = threadIdx.x;
  const float* w = g ? w1 : w0;
  const float* bias = g ? bias1 : bias0;
  float* out = g ? out1 : out0;
  float4 s = {0.f, 0.f, 0.f, 0.f};
#pragma unroll
  for (int c = 0; c < 5; ++c) {
    float4 v = ((const float4*)(partial + (((size_t)c * 2 + g) * B_ + b) * F_))[t];
    s.x += v.x; s.y += v.y; s.z += v.z; s.w += v.w;
  }
  ((float4*)ps)[t] = s;
  __syncthreads();
  const int wave = t >> 6, lane = t & 63;
  for (int oo = 0; oo < 32; ++oo) {
    const int o = wave * 32 + oo;
    const float* wr = w + (size_t)o * F_;
    float a = 0.f;
#pragma unroll
    for (int c = 0; c < 16; ++c) a += wr[c * 64 + lane] * ps[c * 64 + lane];
#pragma unroll
    for (int m = 1; m < 64; m <<= 1) a += __shfl_xor(a, m, 64);
    if (lane == 0) out[b * OD_ + o] = leaky(a * (1.f / 500.f) + bias[o]);
  }
}

// ---- ragged pack (+ totlen from the (p=0,k=0) block) ----
__global__ void k_pack(const float* __restrict__ m0, const float* __restrict__ m1,
                       const float* __restrict__ m2, const float* __restrict__ m3,
                       const int* __restrict__ l0, const int* __restrict__ l1,
                       const int* __restrict__ l2, const int* __restrict__ l3,
                       const float* __restrict__ rw, const float* __restrict__ rb,
                       float* __restrict__ seq, int* __restrict__ tot) {
  __shared__ float xs[DD_];
  const int p = blockIdx.x, b = blockIdx.y, k = blockIdx.z;
  const float* mas = (k == 0) ? m0 : (k == 1) ? m1 : (k == 2) ? m2 : m3;
  const int*   lk  = (k == 0) ? l0 : (k == 1) ? l1 : (k == 2) ? l2 : l3;
  const int len = lk[b];
  if (p >= len) return;  // p==0 never returns (len >= 1)
  int off = 0;
  if (k > 0) off += l0[b];
  if (k > 1) off += l1[b];
  if (k > 2) off += l2[b];
  const int t = threadIdx.x;  // 64
  if (p == 0 && k == 0 && t == 63) tot[b] = l0[b] + l1[b] + l2[b] + l3[b];
  for (int d = t; d < DD_; d += 64) xs[d] = mas[(size_t)(b * LSUB_ + p) * DD_ + d];
  __syncthreads();
  if (t < TD_) {
    float v;
    if (t < TD_ - 2) {
      float a = rb[t];
      const float* w = &rw[t * DD_];
      for (int d = 0; d < DD_; ++d) a += xs[d] * w[d];
      v = a;
    } else if (t == TD_ - 2) {
      v = (k == 0 || k == 2) ? 1.f : 0.f;
    } else {
      v = (k < 2) ? 1.f : 0.f;
    }
    seq[((size_t)b * MAXLEN_ + off + p) * TD_ + t] = v;
  }
}

// ---- qkv projection into per-head K/V planes; 4 rows/block (512 thr).
// Q: [b*512+row][32]; K,V: [b][h][512][8] -> attn staging fully coalesced. ----
__global__ __launch_bounds__(512) void k_qkv(const float* __restrict__ xt,
                                             const float* __restrict__ w,
                                             const float* __restrict__ bias,
                                             const int* __restrict__ tot,
                                             float* __restrict__ Qp,
                                             float* __restrict__ Kp,
                                             float* __restrict__ Vp) {
  __shared__ float xs[4][TD_];
  const int u = threadIdx.x >> 7;        // row-unit 0..3
  const int t = threadIdx.x & 127;
  const int row = blockIdx.x * 4 + u;
  const int b = row >> 9, p = row & (MAXLEN_ - 1);
  const bool alive = p < tot[b];
  if (alive && t < TD_) xs[u][t] = xt[(size_t)row * TD_ + t];
  __syncthreads();
  if (!alive || t >= 3 * TD_) return;
  float a = bias[t];
  const float* wr = &w[t * TD_];
#pragma unroll
  for (int k = 0; k < TD_; ++k) a += xs[u][k] * wr[k];
  if (t < 32) {
    Qp[(size_t)row * 32 + t] = a;
  } else if (t < 64) {
    int h = (t - 32) >> 3, d = (t - 32) & 7;
    Kp[(((size_t)b * NH_ + h) * MAXLEN_ + p) * DH_ + d] = a;
  } else {
    int h = (t - 64) >> 3, d = (t - 64) & 7;
    Vp[(((size_t)b * NH_ + h) * MAXLEN_ + p) * DH_ + d] = a;
  }
}

// ---- attention: one lane-pair per query; K/V staged from contiguous planes ----
__global__ __launch_bounds__(128) void k_attn(const float* __restrict__ Qp,
                                              const float* __restrict__ Kp,
                                              const float* __restrict__ Vp,
                                              const int* __restrict__ tot,
                                              float* __restrict__ obuf) {
  __shared__ float Kl[MAXLEN_ * DH_];
  __shared__ float Vl[MAXLEN_ * DH_];
  const int h = blockIdx.x, b = blockIdx.y, qz = blockIdx.z;
  const int t = threadIdx.x;  // 128
  const int L = tot[b];
  if (qz * 64 >= L) return;
  const float* Kpl = Kp + ((size_t)b * NH_ + h) * MAXLEN_ * DH_;
  const float* Vpl = Vp + ((size_t)b * NH_ + h) * MAXLEN_ * DH_;
  const int n4 = (L * DH_ + 3) >> 2;           // float4 count (plane is 16B-aligned)
  for (int i = t; i < n4; i += 128) {
    ((float4*)Kl)[i] = ((const float4*)Kpl)[i];
    ((float4*)Vl)[i] = ((const float4*)Vpl)[i];
  }
  __syncthreads();
  const int qi = qz * 64 + (t >> 1);
  if (qi >= L) return;
  const int half = t & 1;
  const float scale = 0.35355339059327373f;  // 1/sqrt(8)
  float q[8];
#pragma unroll
  for (int d = 0; d < 8; ++d) q[d] = Qp[((size_t)b * MAXLEN_ + qi) * TD_ + h * 8 + d] * scale;

  float l0 = 0.f, l1 = 0.f;
  float a0[8] = {0, 0, 0, 0, 0, 0, 0, 0};
  float a1[8] = {0, 0, 0, 0, 0, 0, 0, 0};
  int j = half;
  for (; j + 2 < L; j += 4) {
    const float* kr0 = &Kl[j * 8];
    const float* kr1 = &Kl[(j + 2) * 8];
    float s0 = 0.f, s1 = 0.f;
#pragma unroll
    for (int d = 0; d < 8; ++d) { s0 += q[d] * kr0[d]; s1 += q[d] * kr1[d]; }
    float p0 = __expf(s0), p1 = __expf(s1);
    l0 += p0; l1 += p1;
    const float* vr0 = &Vl[j * 8];
    const float* vr1 = &Vl[(j + 2) * 8];
#pragma unroll
    for (int d = 0; d < 8; ++d) { a0[d] += p0 * vr0[d]; a1[d] += p1 * vr1[d]; }
  }
  for (; j < L; j += 2) {
    const float* kr = &Kl[j * 8];
    float s = 0.f;
#pragma unroll
    for (int d = 0; d < 8; ++d) s += q[d] * kr[d];
    float p = __expf(s);
    l0 += p;
    const float* vr = &Vl[j * 8];
#pragma unroll
    for (int d = 0; d < 8; ++d) a0[d] += p * vr[d];
  }
  float l = l0 + l1;
#pragma unroll
  for (int d = 0; d < 8; ++d) a0[d] += a1[d];
  l += __shfl_xor(l, 1);
#pragma unroll
  for (int d = 0; d < 8; ++d) a0[d] += __shfl_xor(a0[d], 1);
  float inv = 1.f / l;
  const int dbase = half * 4;
  float4 o;
  o.x = a0[dbase + 0] * inv; o.y = a0[dbase + 1] * inv;
  o.z = a0[dbase + 2] * inv; o.w = a0[dbase + 3] * inv;
  *(float4*)&obuf[((size_t)b * MAXLEN_ + qi) * TD_ + h * 8 + dbase] = o;
}

// ---- fused post-attention: out-proj + residual + LN1 + FFN + residual + LN2 ----
__global__ __launch_bounds__(128) void k_post(const float* __restrict__ obuf,
                                              const float* __restrict__ ow,
                                              const float* __restrict__ ob,
                                              const float* __restrict__ l1w,
                                              const float* __restrict__ l1b,
                                              const float* __restrict__ f1w,
                                              const float* __restrict__ f1b,
                                              const float* __restrict__ f2w,
                                              const float* __restrict__ f2b,
                                              const float* __restrict__ l2w,
                                              const float* __restrict__ l2b,
                                              const int* __restrict__ tot,
                                              float* __restrict__ xt) {
  const int r = blockIdx.x, t = threadIdx.x;  // 128
  if ((r & (MAXLEN_ - 1)) >= tot[r >> 9]) return;
  __shared__ float xs[TD_];   // LN1 output
  __shared__ float hb[DFF_];
  if (t < TD_) {
    const float* orow = &obuf[(size_t)r * TD_];
    float a = ob[t] + xt[(size_t)r * TD_ + t];
    const float* wr = &ow[t * TD_];
#pragma unroll
    for (int k = 0; k < TD_; ++k) a += orow[k] * wr[k];
    float s1 = a, s2 = a * a;
#pragma unroll
    for (int m = 1; m < 32; m <<= 1) {
      s1 += __shfl_xor(s1, m, 32);
      s2 += __shfl_xor(s2, m, 32);
    }
    float mean = s1 * (1.f / 32.f);
    float var  = s2 * (1.f / 32.f) - mean * mean;
    xs[t] = (a - mean) * rsqrtf(var + EPS_) * l1w[t] + l1b[t];
  }
  __syncthreads();
  {
    float a = f1b[t];
    const float* wr = &f1w[t * TD_];
#pragma unroll
    for (int k = 0; k < TD_; ++k) a += xs[k] * wr[k];
    hb[t] = fmaxf(a, 0.f);
  }
  __syncthreads();
  if (t < TD_) {
    float a = f2b[t] + xs[t];
    const float* wr = &f2w[t * DFF_];
#pragma unroll
    for (int k = 0; k < DFF_; ++k) a += hb[k] * wr[k];
    float s1 = a, s2 = a * a;
#pragma unroll
    for (int m = 1; m < 32; m <<= 1) {
      s1 += __shfl_xor(s1, m, 32);
      s2 += __shfl_xor(s2, m, 32);
    }
    float mean = s1 * (1.f / 32.f);
    float var  = s2 * (1.f / 32.f) - mean * mean;
    xt[(size_t)r * TD_ + t] = (a - mean) * rsqrtf(var + EPS_) * l2w[t] + l2b[t];
  }
}

// ---- fused masked mean + final linear ----
__global__ __launch_bounds__(256) void k_maskfinal(const float* __restrict__ xt,
                                                   const int* __restrict__ tot,
                                                   const float* __restrict__ x1,
                                                   const float* __restrict__ x2,
                                                   const float* __restrict__ fw,
                                                   const float* __restrict__ fb,
                                                   float* __restrict__ out) {
  __shared__ float sbuf[8][32];
  __shared__ float mo[TD_];
  const int b = blockIdx.x, t = threadIdx.x;  // 256
  const int j = t & 31, c = t >> 5;
  const int L = tot[b];
  float s = 0.f;
  for (int p = c; p < L; p += 8) s += xt[((size_t)b * MAXLEN_ + p) * TD_ + j];
  sbuf[c][j] = s;
  __syncthreads();
  if (t < 32) {
    float a = 0.f;
#pragma unroll
    for (int cc = 0; cc < 8; ++cc) a += sbuf[cc][t];
    mo[t] = a / (float)L;
  }
  __syncthreads();
  if (t < 64) {
    float s2 = 0.f;
    for (int i = t; i < 2 * OD_ + TD_; i += 64) {
      float cv = (i < OD_) ? x1[b * OD_ + i]
               : (i < 2 * OD_) ? x2[b * OD_ + (i - OD_)]
               : mo[i - 2 * OD_];
      s2 += fw[i] * cv;
    }
#pragma unroll
    for (int m = 1; m < 64; m <<= 1) s2 += __shfl_xor(s2, m, 64);
    if (t == 0) out[b] = s2 + fb[0];
  }
}

extern "C" void kernel_launch(void* const* d_in, const int* in_sizes, int n_in,
                              void* d_out, int out_size, void* d_ws, size_t ws_size,
                              hipStream_t stream) {
  (void)in_sizes; (void)n_in; (void)out_size; (void)ws_size;
  const float* pro_x[2]  = {(const float*)d_in[0], (const float*)d_in[1]};
  const int*   pro_ei[2] = {(const int*)d_in[2], (const int*)d_in[3]};
  const float* mas[4]    = {(const float*)d_in[6], (const float*)d_in[8],
                            (const float*)d_in[10], (const float*)d_in[12]};
  const int*   lens[4]   = {(const int*)d_in[7], (const int*)d_in[9],
                            (const int*)d_in[11], (const int*)d_in[13]};
  const float* gw[2]  = {(const float*)d_in[14], (const float*)d_in[16]};
  const float* gb[2]  = {(const float*)d_in[15], (const float*)d_in[17]};
  const float* fcw[2] = {(const float*)d_in[18], (const float*)d_in[20]};
  const float* fcb[2] = {(const float*)d_in[19], (const float*)d_in[21]};
  const float* red_w = (const float*)d_in[22];
  const float* red_b = (const float*)d_in[23];
  const float* attn_in_w  = (const float*)d_in[24];
  const float* attn_in_b  = (const float*)d_in[25];
  const float* attn_out_w = (const float*)d_in[26];
  const float* attn_out_b = (const float*)d_in[27];
  const float* ln1_w = (const float*)d_in[28];
  const float* ln1_b = (const float*)d_in[29];
  const float* ln2_w = (const float*)d_in[30];
  const float* ln2_b = (const float*)d_in[31];
  const float* ff1_w = (const float*)d_in[32];
  const float* ff1_b = (const float*)d_in[33];
  const float* ff2_w = (const float*)d_in[34];
  const float* ff2_b = (const float*)d_in[35];
  const float* final_w = (const float*)d_in[36];
  const float* final_b = (const float*)d_in[37];
  float* out = (float*)d_out;

  char* p = (char*)d_ws;
  auto carve = [&](size_t bytes) -> void* {
    void* r = (void*)p;
    p += (bytes + 255) & ~(size_t)255;
    return r;
  };
  unsigned short* xb  = (unsigned short*)carve((size_t)2 * MPAD_ * F_ * 2);
  unsigned short* Wb  = (unsigned short*)carve((size_t)2 * F_ * F_ * 2);
  unsigned short* h   = (unsigned short*)carve((size_t)2 * MPAD_ * F_ * 2);
  unsigned short* aggs = (unsigned short*)carve((size_t)2 * 8 * N_NODES * 128 * 2);
  int*   cnt      = (int*)carve((size_t)2 * N_NODES * 4);
  float* dinv     = (float*)carve((size_t)2 * N_NODES * 4);
  int*   rowstart = (int*)carve((size_t)2 * (N_NODES + 1) * 4);
  int*   cursor   = (int*)carve((size_t)2 * N_NODES * 4);
  int2*  csre     = (int2*)carve((size_t)2 * E_ * 8);
  float* partial  = (float*)carve((size_t)5 * 2 * B_ * F_ * 4);
  float* xg[2];
  xg[0] = (float*)carve((size_t)B_ * OD_ * 4);
  xg[1] = (float*)carve((size_t)B_ * OD_ * 4);
  float* seq    = (float*)carve((size_t)B_ * MAXLEN_ * TD_ * 4);
  float* Qp     = (float*)carve((size_t)B_ * MAXLEN_ * TD_ * 4);
  float* Kp     = (float*)carve((size_t)B_ * NH_ * MAXLEN_ * DH_ * 4);
  float* Vp     = (float*)carve((size_t)B_ * NH_ * MAXLEN_ * DH_ * 4);
  float* obuf   = (float*)carve((size_t)B_ * MAXLEN_ * TD_ * 4);
  int*   totlen = (int*)carve((size_t)B_ * 4);

  // ---- GCN branches (merged across both graphs) ----
  k_prep<<<dim3(1024, 5), 256, 0, stream>>>(pro_x[0], pro_x[1], gw[0], gw[1],
                                            xb, xb + (size_t)MPAD_ * F_,
                                            Wb, Wb + (size_t)F_ * F_, cnt);
  k_gemm256<<<dim3(252, 1, 2), 512, 0, stream>>>(xb, Wb, h);
  k_hist<<<dim3(1000, 2), 256, 0, stream>>>(pro_ei[0], pro_ei[1], cnt, E_, N_NODES);
  k_scan<<<2, 256, 0, stream>>>(cnt, rowstart, cursor, dinv, N_NODES);
  k_scatter<<<dim3(1000, 2), 256, 0, stream>>>(pro_ei[0], pro_ei[1], dinv, cursor,
                                               csre, E_, N_NODES);
  k_gather<<<dim3(8, 1000, 2), 256, 0, stream>>>((const uint4*)h, dinv, rowstart,
                                                 csre, (unsigned*)aggs);
  k_poolpart<<<dim3(B_, 2, 5), 512, 0, stream>>>(aggs, gb[0], gb[1], partial);
  k_fc<<<dim3(B_, 2), 256, 0, stream>>>(partial, fcw[0], fcw[1], fcb[0], fcb[1],
                                        xg[0], xg[1]);

  // ---- ragged pack (+totlen; no memset: dead rows never read) ----
  k_pack<<<dim3(LSUB_, B_, 4), 64, 0, stream>>>(mas[0], mas[1], mas[2], mas[3],
                                                lens[0], lens[1], lens[2], lens[3],
                                                red_w, red_b, seq, totlen);

  // ---- transformer (2 layers) ----
  for (int li = 0; li < 2; ++li) {
    k_qkv<<<(B_ * MAXLEN_) / 4, 512, 0, stream>>>(seq, attn_in_w + (size_t)li * 96 * TD_,
                                                  attn_in_b + (size_t)li * 96, totlen,
                                                  Qp, Kp, Vp);
    k_attn<<<dim3(NH_, B_, 8), 128, 0, stream>>>(Qp, Kp, Vp, totlen, obuf);
    k_post<<<B_ * MAXLEN_, 128, 0, stream>>>(
        obuf, attn_out_w + (size_t)li * TD_ * TD_, attn_out_b + (size_t)li * TD_,
        ln1_w + (size_t)li * TD_, ln1_b + (size_t)li * TD_,
        ff1_w + (size_t)li * DFF_ * TD_, ff1_b + (size_t)li * DFF_,
        ff2_w + (size_t)li * TD_ * DFF_, ff2_b + (size_t)li * TD_,
        ln2_w + (size_t)li * TD_, ln2_b + (size_t)li * TD_, totlen, seq);
  }

  // ---- fused masked mean + final ----
  k_maskfinal<<<B_, 256, 0, stream>>>(seq, totlen, xg[0], xg[1], final_w, final_b, out);
}